// Round 7
// baseline (80.633 us; speedup 1.0000x reference)
//
#include <hip/hip_runtime.h>

// DeepSeek-MLA sparse attention, absorbed formulation, full bf16-MFMA pipeline.
// B=2 NQ=1024 NKV=2048 K=64 D=1024 H=16 LAT=128 HD=64
// Round-7: GEMM K-loop moved from 2-phase full-drain (__syncthreads emits
// vmcnt(0) lgkmcnt(0)) to 3-buffer depth-2 counted-vmcnt pipeline with raw
// s_barrier (T3/T4-lite). vmcnt never drains to 0 in the main loop.
#define NKVc  2048
#define SCALE 0.125f

typedef unsigned short u16;
typedef __attribute__((ext_vector_type(8))) short short8b;     // 8 bf16 (MFMA frag)
typedef __attribute__((ext_vector_type(8))) unsigned short ushort8;
typedef __attribute__((ext_vector_type(4))) float f32x4;

__device__ __forceinline__ u16 f2bf(float f) {
  unsigned int u = __float_as_uint(f);
  return (u16)((u + 0x7FFFu + ((u >> 16) & 1u)) >> 16);   // RNE
}

// ---------------------------------------------------------------------------
// Mega-conversion: all fp32->bf16 prep in ONE dispatch. Unit = 8 elements.
// ---------------------------------------------------------------------------
__device__ __forceinline__ void conv8(const float* __restrict__ in,
                                      u16* __restrict__ out, int j) {
  float4 f0 = ((const float4*)in)[j * 2];
  float4 f1 = ((const float4*)in)[j * 2 + 1];
  ushort4 a, b;
  a.x = f2bf(f0.x); a.y = f2bf(f0.y); a.z = f2bf(f0.z); a.w = f2bf(f0.w);
  b.x = f2bf(f1.x); b.y = f2bf(f1.y); b.z = f2bf(f1.z); b.w = f2bf(f1.w);
  ((ushort4*)out)[j * 2] = a;
  ((ushort4*)out)[j * 2 + 1] = b;
}

__global__ __launch_bounds__(256)
void megaconv(const float* __restrict__ xq, const float* __restrict__ wq,
              const float* __restrict__ xkv, const float* __restrict__ wkvd,
              const float* __restrict__ wkvu, const float* __restrict__ wout,
              u16* __restrict__ xq_bf, u16* __restrict__ wq_bf,
              u16* __restrict__ xkv_bf, u16* __restrict__ wkvd_bf,
              u16* __restrict__ wv_bf, u16* __restrict__ wout_bf,
              u16* __restrict__ wkt) {
  int i = blockIdx.x * 256 + threadIdx.x;
  if (i < 262144) { conv8(xq, xq_bf, i); return; }
  if (i < 393216) { conv8(wq, wq_bf, i - 262144); return; }
  if (i < 917504) { conv8(xkv, xkv_bf, i - 393216); return; }
  if (i < 933888) { conv8(wkvd, wkvd_bf, i - 917504); return; }
  if (i < 950272) { conv8(wkvu + 131072, wv_bf, i - 933888); return; }
  if (i < 1081344) { conv8(wout, wout_bf, i - 950272); return; }
  {
    int o = (i - 1081344) * 8;          // 8 consecutive hd in one (h,l)
    int hd0 = o & 63;
    int l = (o >> 6) & 127;
    int h = o >> 13;
    const float* src = wkvu + (h * 64 + hd0) * 128 + l;
    ushort8 v;
#pragma unroll
    for (int j = 0; j < 8; ++j) v[j] = f2bf(src[j * 128]);
    *(ushort8*)&wkt[o] = v;
  }
}

// split-K reduce, bf16 out: dst[i] = bf16(sum_{p<4} src[p*n + i])
__global__ __launch_bounds__(256)
void reduce4b(u16* __restrict__ dst, const float* __restrict__ src, int n4) {
  int i = blockIdx.x * 256 + threadIdx.x;
  if (i >= n4) return;
  const float4* s = (const float4*)src;
  float4 a = s[i], b = s[i + n4], c = s[i + 2 * n4], d = s[i + 3 * n4];
  ushort4 v;
  v.x = f2bf(a.x + b.x + c.x + d.x); v.y = f2bf(a.y + b.y + c.y + d.y);
  v.z = f2bf(a.z + b.z + c.z + d.z); v.w = f2bf(a.w + b.w + c.w + d.w);
  ((ushort4*)dst)[i] = v;
}

// ---------------------------------------------------------------------------
// bf16 MFMA GEMM-NT, z-batched: C[m,n] = sum_k A[m,k]*B[n,k]
// BM=64, BN=64, BK=32, 256 thr / 4 waves (2x2); wave tile 32x32.
// 3-buffer depth-2 counted-vmcnt pipeline:
//   prologue: stage(0), stage(1)
//   iter t:   vmcnt(2) [tile t done, t+1 in flight] ; s_barrier ;
//             stage(t+2 -> buf (t+2)%3) ; compute(buf t%3)
// buf (t+2)%3 was last read at compute(t-1), which precedes the iter-t
// barrier in every wave -> no overwrite race. Tail drains vmcnt(0) once.
// ---------------------------------------------------------------------------
template<int BM, bool OBF>
__global__ __launch_bounds__(256)
void gemm_bf16_nt(const u16* __restrict__ A, int lda, long sAz,
                  const u16* __restrict__ B, int ldb, long sBz,
                  float* __restrict__ C, u16* __restrict__ Cb,
                  int ldc, long sCz, int K) {
  A += (size_t)blockIdx.z * sAz;
  B += (size_t)blockIdx.z * sBz;
  constexpr int ASLOT = BM * 4;                  // 16B slots in A tile
  constexpr int MF = BM / 32;                    // m-frags per wave
  static_assert(BM == 64, "vmcnt immediates assume 2 loads/stage");
  __shared__ __align__(16) u16 As[3][ASLOT * 8];
  __shared__ __align__(16) u16 Bs[3][256 * 8];
  const int tid = threadIdx.x;
  const int w = tid >> 6, lane = tid & 63;
  const int bm = blockIdx.y * BM, bn = blockIdx.x * 64;
  const int wr = w >> 1, wc = w & 1;

  f32x4 acc[MF][2] = {};

  auto stage = [&](int buf, int t) {
    const int k0 = t << 5;
#pragma unroll
    for (int tt = 0; tt < BM / 64; ++tt) {
      int s = w * (ASLOT / 4) + tt * 64 + lane;
      int row = s >> 2;
      int kc = (s & 3) ^ ((row >> 1) & 3);
      const u16* g = A + (size_t)(bm + row) * lda + (k0 + kc * 8);
      __builtin_amdgcn_global_load_lds(
          (const __attribute__((address_space(1))) unsigned int*)g,
          (__attribute__((address_space(3))) unsigned int*)&As[buf][(w * (ASLOT / 4) + tt * 64) * 8],
          16, 0, 0);
    }
    {
      int s = w * 64 + lane;
      int row = s >> 2;
      int kc = (s & 3) ^ ((row >> 1) & 3);
      const u16* g = B + (size_t)(bn + row) * ldb + (k0 + kc * 8);
      __builtin_amdgcn_global_load_lds(
          (const __attribute__((address_space(1))) unsigned int*)g,
          (__attribute__((address_space(3))) unsigned int*)&Bs[buf][(w * 64) * 8],
          16, 0, 0);
    }
  };

  auto compute = [&](int buf) {
    short8b a[MF], b[2];
#pragma unroll
    for (int m = 0; m < MF; ++m) {
      int row = wr * (BM / 2) + m * 16 + (lane & 15);
      int slot = row * 4 + ((lane >> 4) ^ ((row >> 1) & 3));
      a[m] = *(const short8b*)&As[buf][slot * 8];
    }
#pragma unroll
    for (int n = 0; n < 2; ++n) {
      int col = wc * 32 + n * 16 + (lane & 15);
      int slot = col * 4 + ((lane >> 4) ^ ((col >> 1) & 3));
      b[n] = *(const short8b*)&Bs[buf][slot * 8];
    }
#pragma unroll
    for (int m = 0; m < MF; ++m)
#pragma unroll
      for (int n = 0; n < 2; ++n)
        acc[m][n] = __builtin_amdgcn_mfma_f32_16x16x32_bf16(a[m], b[n], acc[m][n], 0, 0, 0);
  };

  const int nk = K >> 5;
  stage(0, 0);
  if (nk > 1) stage(1, 1);
  for (int t = 0; t < nk; ++t) {
    if (t + 1 < nk) asm volatile("s_waitcnt vmcnt(2)" ::: "memory");
    else            asm volatile("s_waitcnt vmcnt(0)" ::: "memory");
    __builtin_amdgcn_s_barrier();
    __builtin_amdgcn_sched_barrier(0);   // pin: no hoisting of reads above barrier
    if (t + 2 < nk) stage((t + 2) % 3, t + 2);
    compute(t % 3);
  }

#pragma unroll
  for (int m = 0; m < MF; ++m) {
    int row0 = bm + wr * (BM / 2) + m * 16 + (lane >> 4) * 4;
#pragma unroll
    for (int n = 0; n < 2; ++n) {
      int col = bn + wc * 32 + n * 16 + (lane & 15);
      if constexpr (OBF) {
        u16* Cz = Cb + (size_t)blockIdx.z * sCz;
#pragma unroll
        for (int r = 0; r < 4; ++r)
          Cz[(size_t)(row0 + r) * ldc + col] = f2bf(acc[m][n][r]);
      } else {
        float* Cz = C + (size_t)blockIdx.z * sCz;
#pragma unroll
        for (int r = 0; r < 4; ++r)
          Cz[(size_t)(row0 + r) * ldc + col] = acc[m][n][r];
      }
    }
  }
}

// ---------------------------------------------------------------------------
// Fused sparse attention in latent space, bf16 MFMA. One block per (b,q).
// (unchanged from round 6 -- proven correct)
// ---------------------------------------------------------------------------
__global__ __launch_bounds__(256)
void attn_mfma(const u16* __restrict__ c_kvb,   // (B, 2048, 128) bf16
               const u16* __restrict__ q_latb,  // (BQ, 16, 128) bf16
               const int* __restrict__ indices, // (BQ, 64)
               u16* __restrict__ cw_bf) {       // (BQ, 16, 128) bf16
  __shared__ __align__(16) u16 qls[256 * 8];
  __shared__ __align__(16) u16 csa[1024 * 8];
  __shared__ __align__(16) u16 cst[128 * 72];
  __shared__ __align__(16) u16 pT[16 * 72];
  __shared__ __align__(16) float redmax[64];
  __shared__ __align__(16) float redsum[64];
  __shared__ __align__(16) u16 outst[2048];

  const int tid = threadIdx.x;
  const int w = tid >> 6, lane = tid & 63;
  const int bq = blockIdx.x;
  const int b = bq >> 10;

  {
    int h = tid >> 4, c = tid & 15;
    ushort8 v = *(const ushort8*)(q_latb + (size_t)bq * 2048 + tid * 8);
    *(ushort8*)&qls[(h * 16 + (c ^ h)) * 8] = v;
  }
  {
    int kidx = indices[bq * 64 + lane];
    const u16* src = c_kvb + ((size_t)b * NKVc + kidx) * 128 + w * 32;
    ushort8 v[4];
#pragma unroll
    for (int t = 0; t < 4; ++t) v[t] = *(const ushort8*)(src + t * 8);
#pragma unroll
    for (int t = 0; t < 4; ++t) {
      int c = w * 4 + t;
      *(ushort8*)&csa[(lane * 16 + (c ^ (lane & 15))) * 8] = v[t];
    }
#pragma unroll
    for (int t = 0; t < 4; ++t)
#pragma unroll
      for (int j = 0; j < 8; ++j)
        cst[(w * 32 + t * 8 + j) * 72 + lane] = v[t][j];
  }
  __syncthreads();

  f32x4 sacc = {};
#pragma unroll
  for (int kc = 0; kc < 4; ++kc) {
    int ar = w * 16 + (lane & 15);
    int ac = kc * 4 + (lane >> 4);
    short8b av = *(const short8b*)&csa[(ar * 16 + (ac ^ (ar & 15))) * 8];
    int bh = lane & 15;
    short8b bv = *(const short8b*)&qls[(bh * 16 + (ac ^ bh)) * 8];
    sacc = __builtin_amdgcn_mfma_f32_16x16x32_bf16(av, bv, sacc, 0, 0, 0);
  }
  float s0 = sacc[0] * SCALE, s1 = sacc[1] * SCALE;
  float s2 = sacc[2] * SCALE, s3 = sacc[3] * SCALE;
  float mx = fmaxf(fmaxf(s0, s1), fmaxf(s2, s3));
  mx = fmaxf(mx, __shfl_xor(mx, 16));
  mx = fmaxf(mx, __shfl_xor(mx, 32));
  if (lane < 16) redmax[w * 16 + lane] = mx;
  __syncthreads();
  const int h = lane & 15;
  float m4 = fmaxf(fmaxf(redmax[h], redmax[16 + h]),
                   fmaxf(redmax[32 + h], redmax[48 + h]));
  float p0 = __expf(s0 - m4), p1 = __expf(s1 - m4);
  float p2 = __expf(s2 - m4), p3 = __expf(s3 - m4);
  float sm = p0 + p1 + p2 + p3;
  sm += __shfl_xor(sm, 16);
  sm += __shfl_xor(sm, 32);
  if (lane < 16) redsum[w * 16 + lane] = sm;
  __syncthreads();
  float tot = redsum[h] + redsum[16 + h] + redsum[32 + h] + redsum[48 + h];
  float inv = 1.0f / tot;
  {
    ushort4 pw;
    pw.x = f2bf(p0 * inv); pw.y = f2bf(p1 * inv);
    pw.z = f2bf(p2 * inv); pw.w = f2bf(p3 * inv);
    *(ushort4*)&pT[h * 72 + w * 16 + (lane >> 4) * 4] = pw;
  }
  __syncthreads();

  f32x4 pacc0 = {}, pacc1 = {};
#pragma unroll
  for (int kc = 0; kc < 2; ++kc) {
    short8b pa = *(const short8b*)&pT[(lane & 15) * 72 + kc * 32 + (lane >> 4) * 8];
    int cch = kc * 4 + (lane >> 4);
    int n0 = w * 32 + (lane & 15);
    short8b b0 = *(const short8b*)&cst[n0 * 72 + cch * 8];
    short8b b1 = *(const short8b*)&cst[(n0 + 16) * 72 + cch * 8];
    pacc0 = __builtin_amdgcn_mfma_f32_16x16x32_bf16(pa, b0, pacc0, 0, 0, 0);
    pacc1 = __builtin_amdgcn_mfma_f32_16x16x32_bf16(pa, b1, pacc1, 0, 0, 0);
  }
#pragma unroll
  for (int r = 0; r < 4; ++r) {
    int hh = (lane >> 4) * 4 + r;
    outst[hh * 128 + w * 32 + (lane & 15)] = f2bf(pacc0[r]);
    outst[hh * 128 + w * 32 + 16 + (lane & 15)] = f2bf(pacc1[r]);
  }
  __syncthreads();
  *(ushort8*)(cw_bf + (size_t)bq * 2048 + tid * 8) = *(const ushort8*)&outst[tid * 8];
}

extern "C" void kernel_launch(void* const* d_in, const int* in_sizes, int n_in,
                              void* d_out, int out_size, void* d_ws, size_t ws_size,
                              hipStream_t stream) {
  const float* x_q    = (const float*)d_in[0];
  const float* x_kv   = (const float*)d_in[1];
  const int*   idx    = (const int*)  d_in[2];
  const float* W_q    = (const float*)d_in[3];
  const float* W_kvd  = (const float*)d_in[4];
  const float* W_kvu  = (const float*)d_in[5];
  const float* W_out  = (const float*)d_in[6];
  float* out = (float*)d_out;

  // byte-offset workspace carve; top = 42 MB (proven footprint)
  char* wsb = (char*)d_ws;
  u16* xq_bf   = (u16*)(wsb + 0);                            // 4 MB
  u16* wq_bf   = (u16*)(wsb + (4u << 20));                   // 2 MB
  u16* xkv_bf  = (u16*)(wsb + (6u << 20));                   // 8 MB
  u16* wkvd_bf = (u16*)(wsb + (14u << 20));                  // 256 KB
  u16* wkt     = (u16*)(wsb + (14u << 20) + (256u << 10));   // 256 KB
  u16* wv_bf   = (u16*)(wsb + (14u << 20) + (512u << 10));   // 256 KB
  u16* wout_bf = (u16*)(wsb + (14u << 20) + (768u << 10));   // 2 MB
  u16* q_bf    = (u16*)(wsb + (17u << 20));                  // 4 MB
  u16* c_kvb   = (u16*)(wsb + (21u << 20));                  // 1 MB
  u16* qlat_bf = (u16*)(wsb + (22u << 20));                  // 8 MB
  u16* cw_bf   = (u16*)(wsb + (30u << 20));                  // 8 MB
  u16* o_bf    = (u16*)(wsb + (38u << 20));                  // 4 MB
  float* pbuf  = (float*)(wsb + (30u << 20));                // 8 MB, alias cw (dead pre-attn)

  // C0: all conversions in one dispatch
  megaconv<<<dim3(4288), 256, 0, stream>>>(x_q, W_q, x_kv, W_kvd, W_kvu, W_out,
                                           xq_bf, wq_bf, xkv_bf, wkvd_bf,
                                           wv_bf, wout_bf, wkt);

  // K2: c_kvb = bf16(x_kv @ W_kvd^T), split-K x4 (M=4096,N=128,K=1024)
  gemm_bf16_nt<64, false><<<dim3(2, 64, 4), 256, 0, stream>>>(
      xkv_bf, 1024, 256, wkvd_bf, 1024, 256, pbuf, nullptr,
      128, (long)4096 * 128, 256);
  reduce4b<<<dim3(512), 256, 0, stream>>>(c_kvb, pbuf, 131072);

  // K1: q_bf = bf16(x_q @ W_q^T)  (M=2048,N=1024,K=1024) -> 512 blocks
  gemm_bf16_nt<64, true><<<dim3(16, 32, 1), 256, 0, stream>>>(
      xq_bf, 1024, 0, wq_bf, 1024, 0, nullptr, q_bf, 1024, 0, 1024);

  // K3: qlat_bf[bq,h,:] = bf16(q[bq,h*64:] @ wkt[h]^T)  (M=2048,N=128,K=64, z=h)
  gemm_bf16_nt<64, true><<<dim3(2, 32, 16), 256, 0, stream>>>(
      q_bf, 1024, 64, wkt, 64, 8192, nullptr, qlat_bf, 2048, 128, 64);

  // K4: fused gather + latent scores + softmax + latent PV (bf16 MFMA)
  attn_mfma<<<dim3(2048), 256, 0, stream>>>(c_kvb, qlat_bf, idx, cw_bf);

  // K5: o_bf[bq,h*64+n] = bf16(cw[bq,h,:] @ W_v[h]^T)  (M=2048,N=64,K=128, z=h)
  gemm_bf16_nt<64, true><<<dim3(1, 32, 16), 256, 0, stream>>>(
      cw_bf, 2048, 128, wv_bf, 128, 8192, nullptr, o_bf, 1024, 64, 128);

  // K6: out = o @ W_out^T  (fp32 out)  (M=2048,N=1024,K=1024) -> 512 blocks
  gemm_bf16_nt<64, false><<<dim3(16, 32, 1), 256, 0, stream>>>(
      o_bf, 1024, 0, wout_bf, 1024, 0, out, nullptr, 1024, 0, 1024);
}

// Round 8
// 70.863 us; speedup vs baseline: 1.1379x; 1.1379x over previous
//
#include <hip/hip_runtime.h>

// DeepSeek-MLA sparse attention, absorbed formulation, full bf16-MFMA pipeline.
// B=2 NQ=1024 NKV=2048 K=64 D=1024 H=16 LAT=128 HD=64
// Round-8: REVERT round-7 pipeline (regressed 75->80.6, reproducing m141's
// sched_barrier regression). GEMM K-loop is round-6's proven 2-phase drain.
// NEW: dispatch multiplexing -- D1 = K1||K2, D2 = K3||reduce4b (8->6
// dispatches), per-block routing on blockIdx.x. No arithmetic changes.
#define NKVc  2048
#define SCALE 0.125f

typedef unsigned short u16;
typedef __attribute__((ext_vector_type(8))) short short8b;     // 8 bf16 (MFMA frag)
typedef __attribute__((ext_vector_type(8))) unsigned short ushort8;
typedef __attribute__((ext_vector_type(4))) float f32x4;

__device__ __forceinline__ u16 f2bf(float f) {
  unsigned int u = __float_as_uint(f);
  return (u16)((u + 0x7FFFu + ((u >> 16) & 1u)) >> 16);   // RNE
}

// ---------------------------------------------------------------------------
// Mega-conversion: all fp32->bf16 prep in ONE dispatch. Unit = 8 elements.
// ---------------------------------------------------------------------------
__device__ __forceinline__ void conv8(const float* __restrict__ in,
                                      u16* __restrict__ out, int j) {
  float4 f0 = ((const float4*)in)[j * 2];
  float4 f1 = ((const float4*)in)[j * 2 + 1];
  ushort4 a, b;
  a.x = f2bf(f0.x); a.y = f2bf(f0.y); a.z = f2bf(f0.z); a.w = f2bf(f0.w);
  b.x = f2bf(f1.x); b.y = f2bf(f1.y); b.z = f2bf(f1.z); b.w = f2bf(f1.w);
  ((ushort4*)out)[j * 2] = a;
  ((ushort4*)out)[j * 2 + 1] = b;
}

__global__ __launch_bounds__(256)
void megaconv(const float* __restrict__ xq, const float* __restrict__ wq,
              const float* __restrict__ xkv, const float* __restrict__ wkvd,
              const float* __restrict__ wkvu, const float* __restrict__ wout,
              u16* __restrict__ xq_bf, u16* __restrict__ wq_bf,
              u16* __restrict__ xkv_bf, u16* __restrict__ wkvd_bf,
              u16* __restrict__ wv_bf, u16* __restrict__ wout_bf,
              u16* __restrict__ wkt) {
  int i = blockIdx.x * 256 + threadIdx.x;
  if (i < 262144) { conv8(xq, xq_bf, i); return; }
  if (i < 393216) { conv8(wq, wq_bf, i - 262144); return; }
  if (i < 917504) { conv8(xkv, xkv_bf, i - 393216); return; }
  if (i < 933888) { conv8(wkvd, wkvd_bf, i - 917504); return; }
  if (i < 950272) { conv8(wkvu + 131072, wv_bf, i - 933888); return; }
  if (i < 1081344) { conv8(wout, wout_bf, i - 950272); return; }
  {
    int o = (i - 1081344) * 8;          // 8 consecutive hd in one (h,l)
    int hd0 = o & 63;
    int l = (o >> 6) & 127;
    int h = o >> 13;
    const float* src = wkvu + (h * 64 + hd0) * 128 + l;
    ushort8 v;
#pragma unroll
    for (int j = 0; j < 8; ++j) v[j] = f2bf(src[j * 128]);
    *(ushort8*)&wkt[o] = v;
  }
}

// ---------------------------------------------------------------------------
// bf16 MFMA GEMM-NT body (BM=64, BN=64, BK=32, 256 thr / 4 waves 2x2).
// EXACT round-6 structure: both-sides XOR swizzle + global_load_lds w=16 +
// 2-phase double buffer with full drain per K-step (proven 75.0 us config;
// round-7's counted-vmcnt variant regressed and was reverted).
// obf (runtime): epilogue writes bf16 to Cb, else fp32 to C.
// ---------------------------------------------------------------------------
__device__ __forceinline__ void gemm_body(
    int bx, int by, int bz,
    const u16* __restrict__ A, int lda, long sAz,
    const u16* __restrict__ B, int ldb, long sBz,
    float* __restrict__ C, u16* __restrict__ Cb,
    int ldc, long sCz, int K, bool obf) {
  A += (size_t)bz * sAz;
  B += (size_t)bz * sBz;
  __shared__ __align__(16) u16 As[2][256 * 8];   // 2 x 4 KB
  __shared__ __align__(16) u16 Bs[2][256 * 8];   // 2 x 4 KB
  const int tid = threadIdx.x;
  const int w = tid >> 6, lane = tid & 63;
  const int bm = by * 64, bn = bx * 64;
  const int wr = w >> 1, wc = w & 1;

  f32x4 acc[2][2] = {};

  auto stage = [&](int buf, int k0) {
    {
      int s = w * 64 + lane;
      int row = s >> 2;
      int kc = (s & 3) ^ ((row >> 1) & 3);
      const u16* g = A + (size_t)(bm + row) * lda + (k0 + kc * 8);
      __builtin_amdgcn_global_load_lds(
          (const __attribute__((address_space(1))) unsigned int*)g,
          (__attribute__((address_space(3))) unsigned int*)&As[buf][(w * 64) * 8],
          16, 0, 0);
    }
    {
      int s = w * 64 + lane;
      int row = s >> 2;
      int kc = (s & 3) ^ ((row >> 1) & 3);
      const u16* g = B + (size_t)(bn + row) * ldb + (k0 + kc * 8);
      __builtin_amdgcn_global_load_lds(
          (const __attribute__((address_space(1))) unsigned int*)g,
          (__attribute__((address_space(3))) unsigned int*)&Bs[buf][(w * 64) * 8],
          16, 0, 0);
    }
  };

  auto compute = [&](int buf) {
    short8b a[2], b[2];
#pragma unroll
    for (int m = 0; m < 2; ++m) {
      int row = wr * 32 + m * 16 + (lane & 15);
      int slot = row * 4 + ((lane >> 4) ^ ((row >> 1) & 3));
      a[m] = *(const short8b*)&As[buf][slot * 8];
    }
#pragma unroll
    for (int n = 0; n < 2; ++n) {
      int col = wc * 32 + n * 16 + (lane & 15);
      int slot = col * 4 + ((lane >> 4) ^ ((col >> 1) & 3));
      b[n] = *(const short8b*)&Bs[buf][slot * 8];
    }
#pragma unroll
    for (int m = 0; m < 2; ++m)
#pragma unroll
      for (int n = 0; n < 2; ++n)
        acc[m][n] = __builtin_amdgcn_mfma_f32_16x16x32_bf16(a[m], b[n], acc[m][n], 0, 0, 0);
  };

  stage(0, 0);
  asm volatile("s_waitcnt vmcnt(0)" ::: "memory");
  __syncthreads();
  const int nk = K >> 5;
  for (int t = 0; t < nk; ++t) {
    int cur = t & 1;
    if (t + 1 < nk) stage(cur ^ 1, (t + 1) << 5);
    compute(cur);
    asm volatile("s_waitcnt vmcnt(0)" ::: "memory");
    __syncthreads();
  }

#pragma unroll
  for (int m = 0; m < 2; ++m) {
    int row0 = bm + wr * 32 + m * 16 + (lane >> 4) * 4;
#pragma unroll
    for (int n = 0; n < 2; ++n) {
      int col = bn + wc * 32 + n * 16 + (lane & 15);
      if (obf) {
        u16* Cz = Cb + (size_t)bz * sCz;
#pragma unroll
        for (int r = 0; r < 4; ++r)
          Cz[(size_t)(row0 + r) * ldc + col] = f2bf(acc[m][n][r]);
      } else {
        float* Cz = C + (size_t)bz * sCz;
#pragma unroll
        for (int r = 0; r < 4; ++r)
          Cz[(size_t)(row0 + r) * ldc + col] = acc[m][n][r];
      }
    }
  }
}

// standalone wrapper (K5, K6)
__global__ __launch_bounds__(256)
void gemm_nt_g(const u16* __restrict__ A, int lda, long sAz,
               const u16* __restrict__ B, int ldb, long sBz,
               float* __restrict__ C, u16* __restrict__ Cb,
               int ldc, long sCz, int K, int obf) {
  gemm_body(blockIdx.x, blockIdx.y, blockIdx.z, A, lda, sAz, B, ldb, sBz,
            C, Cb, ldc, sCz, K, obf != 0);
}

// ---------------------------------------------------------------------------
// D1: K1 || K2 in one dispatch (both depend only on megaconv).
//   blocks [0,512):    K1  q_bf = bf16(x_q @ W_q^T), grid (16,32)
//   blocks [512,1024): K2  pbuf[z] = x_kv @ W_kvd^T partials, grid (2,64,4)
// ---------------------------------------------------------------------------
__global__ __launch_bounds__(256)
void d1_qproj_ckv(const u16* __restrict__ xq_bf, const u16* __restrict__ wq_bf,
                  const u16* __restrict__ xkv_bf, const u16* __restrict__ wkvd_bf,
                  u16* __restrict__ q_bf, float* __restrict__ pbuf) {
  int b = blockIdx.x;
  if (b < 512) {
    gemm_body(b & 15, b >> 4, 0, xq_bf, 1024, 0, wq_bf, 1024, 0,
              nullptr, q_bf, 1024, 0, 1024, true);
  } else {
    int b2 = b - 512;
    gemm_body(b2 & 1, (b2 >> 1) & 63, b2 >> 7, xkv_bf, 1024, 256,
              wkvd_bf, 1024, 256, pbuf, nullptr, 128, (long)4096 * 128,
              256, false);
  }
}

// ---------------------------------------------------------------------------
// D2: K3 || reduce4b in one dispatch (K3 needs q_bf<-D1; reduce needs pbuf<-D1).
//   blocks [0,1024):    K3  qlat_bf[z=h] = bf16(q @ wkt[h]^T), grid (2,32,16)
//   blocks [1024,1536): reduce: c_kvb[i] = bf16(sum_p pbuf[p][i]), 4-way f4
// ---------------------------------------------------------------------------
__global__ __launch_bounds__(256)
void d2_qlat_reduce(const u16* __restrict__ q_bf, const u16* __restrict__ wkt,
                    u16* __restrict__ qlat_bf, const float* __restrict__ pbuf,
                    u16* __restrict__ c_kvb) {
  int b = blockIdx.x;
  if (b >= 1024) {
    int i = (b - 1024) * 256 + threadIdx.x;   // n4 = 131072
    const float4* s = (const float4*)pbuf;
    float4 a = s[i], bb = s[i + 131072], c = s[i + 2 * 131072], d = s[i + 3 * 131072];
    ushort4 v;
    v.x = f2bf(a.x + bb.x + c.x + d.x); v.y = f2bf(a.y + bb.y + c.y + d.y);
    v.z = f2bf(a.z + bb.z + c.z + d.z); v.w = f2bf(a.w + bb.w + c.w + d.w);
    ((ushort4*)c_kvb)[i] = v;
    return;
  }
  int bz = b >> 6, r = b & 63;
  gemm_body(r & 1, r >> 1, bz, q_bf, 1024, 64, wkt, 64, 8192,
            nullptr, qlat_bf, 2048, 128, 64, true);
}

// ---------------------------------------------------------------------------
// Fused sparse attention in latent space, bf16 MFMA. One block per (b,q).
// (unchanged -- proven correct)
// ---------------------------------------------------------------------------
__global__ __launch_bounds__(256)
void attn_mfma(const u16* __restrict__ c_kvb,   // (B, 2048, 128) bf16
               const u16* __restrict__ q_latb,  // (BQ, 16, 128) bf16
               const int* __restrict__ indices, // (BQ, 64)
               u16* __restrict__ cw_bf) {       // (BQ, 16, 128) bf16
  __shared__ __align__(16) u16 qls[256 * 8];
  __shared__ __align__(16) u16 csa[1024 * 8];
  __shared__ __align__(16) u16 cst[128 * 72];
  __shared__ __align__(16) u16 pT[16 * 72];
  __shared__ __align__(16) float redmax[64];
  __shared__ __align__(16) float redsum[64];
  __shared__ __align__(16) u16 outst[2048];

  const int tid = threadIdx.x;
  const int w = tid >> 6, lane = tid & 63;
  const int bq = blockIdx.x;
  const int b = bq >> 10;

  {
    int h = tid >> 4, c = tid & 15;
    ushort8 v = *(const ushort8*)(q_latb + (size_t)bq * 2048 + tid * 8);
    *(ushort8*)&qls[(h * 16 + (c ^ h)) * 8] = v;
  }
  {
    int kidx = indices[bq * 64 + lane];
    const u16* src = c_kvb + ((size_t)b * NKVc + kidx) * 128 + w * 32;
    ushort8 v[4];
#pragma unroll
    for (int t = 0; t < 4; ++t) v[t] = *(const ushort8*)(src + t * 8);
#pragma unroll
    for (int t = 0; t < 4; ++t) {
      int c = w * 4 + t;
      *(ushort8*)&csa[(lane * 16 + (c ^ (lane & 15))) * 8] = v[t];
    }
#pragma unroll
    for (int t = 0; t < 4; ++t)
#pragma unroll
      for (int j = 0; j < 8; ++j)
        cst[(w * 32 + t * 8 + j) * 72 + lane] = v[t][j];
  }
  __syncthreads();

  f32x4 sacc = {};
#pragma unroll
  for (int kc = 0; kc < 4; ++kc) {
    int ar = w * 16 + (lane & 15);
    int ac = kc * 4 + (lane >> 4);
    short8b av = *(const short8b*)&csa[(ar * 16 + (ac ^ (ar & 15))) * 8];
    int bh = lane & 15;
    short8b bv = *(const short8b*)&qls[(bh * 16 + (ac ^ bh)) * 8];
    sacc = __builtin_amdgcn_mfma_f32_16x16x32_bf16(av, bv, sacc, 0, 0, 0);
  }
  float s0 = sacc[0] * SCALE, s1 = sacc[1] * SCALE;
  float s2 = sacc[2] * SCALE, s3 = sacc[3] * SCALE;
  float mx = fmaxf(fmaxf(s0, s1), fmaxf(s2, s3));
  mx = fmaxf(mx, __shfl_xor(mx, 16));
  mx = fmaxf(mx, __shfl_xor(mx, 32));
  if (lane < 16) redmax[w * 16 + lane] = mx;
  __syncthreads();
  const int h = lane & 15;
  float m4 = fmaxf(fmaxf(redmax[h], redmax[16 + h]),
                   fmaxf(redmax[32 + h], redmax[48 + h]));
  float p0 = __expf(s0 - m4), p1 = __expf(s1 - m4);
  float p2 = __expf(s2 - m4), p3 = __expf(s3 - m4);
  float sm = p0 + p1 + p2 + p3;
  sm += __shfl_xor(sm, 16);
  sm += __shfl_xor(sm, 32);
  if (lane < 16) redsum[w * 16 + lane] = sm;
  __syncthreads();
  float tot = redsum[h] + redsum[16 + h] + redsum[32 + h] + redsum[48 + h];
  float inv = 1.0f / tot;
  {
    ushort4 pw;
    pw.x = f2bf(p0 * inv); pw.y = f2bf(p1 * inv);
    pw.z = f2bf(p2 * inv); pw.w = f2bf(p3 * inv);
    *(ushort4*)&pT[h * 72 + w * 16 + (lane >> 4) * 4] = pw;
  }
  __syncthreads();

  f32x4 pacc0 = {}, pacc1 = {};
#pragma unroll
  for (int kc = 0; kc < 2; ++kc) {
    short8b pa = *(const short8b*)&pT[(lane & 15) * 72 + kc * 32 + (lane >> 4) * 8];
    int cch = kc * 4 + (lane >> 4);
    int n0 = w * 32 + (lane & 15);
    short8b b0 = *(const short8b*)&cst[n0 * 72 + cch * 8];
    short8b b1 = *(const short8b*)&cst[(n0 + 16) * 72 + cch * 8];
    pacc0 = __builtin_amdgcn_mfma_f32_16x16x32_bf16(pa, b0, pacc0, 0, 0, 0);
    pacc1 = __builtin_amdgcn_mfma_f32_16x16x32_bf16(pa, b1, pacc1, 0, 0, 0);
  }
#pragma unroll
  for (int r = 0; r < 4; ++r) {
    int hh = (lane >> 4) * 4 + r;
    outst[hh * 128 + w * 32 + (lane & 15)] = f2bf(pacc0[r]);
    outst[hh * 128 + w * 32 + 16 + (lane & 15)] = f2bf(pacc1[r]);
  }
  __syncthreads();
  *(ushort8*)(cw_bf + (size_t)bq * 2048 + tid * 8) = *(const ushort8*)&outst[tid * 8];
}

extern "C" void kernel_launch(void* const* d_in, const int* in_sizes, int n_in,
                              void* d_out, int out_size, void* d_ws, size_t ws_size,
                              hipStream_t stream) {
  const float* x_q    = (const float*)d_in[0];
  const float* x_kv   = (const float*)d_in[1];
  const int*   idx    = (const int*)  d_in[2];
  const float* W_q    = (const float*)d_in[3];
  const float* W_kvd  = (const float*)d_in[4];
  const float* W_kvu  = (const float*)d_in[5];
  const float* W_out  = (const float*)d_in[6];
  float* out = (float*)d_out;

  // byte-offset workspace carve; top = 42 MB (proven footprint)
  char* wsb = (char*)d_ws;
  u16* xq_bf   = (u16*)(wsb + 0);                            // 4 MB
  u16* wq_bf   = (u16*)(wsb + (4u << 20));                   // 2 MB
  u16* xkv_bf  = (u16*)(wsb + (6u << 20));                   // 8 MB
  u16* wkvd_bf = (u16*)(wsb + (14u << 20));                  // 256 KB
  u16* wkt     = (u16*)(wsb + (14u << 20) + (256u << 10));   // 256 KB
  u16* wv_bf   = (u16*)(wsb + (14u << 20) + (512u << 10));   // 256 KB
  u16* wout_bf = (u16*)(wsb + (14u << 20) + (768u << 10));   // 2 MB
  u16* q_bf    = (u16*)(wsb + (17u << 20));                  // 4 MB
  u16* c_kvb   = (u16*)(wsb + (21u << 20));                  // 1 MB
  u16* qlat_bf = (u16*)(wsb + (22u << 20));                  // 8 MB
  u16* cw_bf   = (u16*)(wsb + (30u << 20));                  // 8 MB
  u16* o_bf    = (u16*)(wsb + (38u << 20));                  // 4 MB
  float* pbuf  = (float*)(wsb + (30u << 20));                // 8 MB, alias cw (dead pre-attn)

  // C0: all conversions in one dispatch
  megaconv<<<dim3(4288), 256, 0, stream>>>(x_q, W_q, x_kv, W_kvd, W_kvu, W_out,
                                           xq_bf, wq_bf, xkv_bf, wkvd_bf,
                                           wv_bf, wout_bf, wkt);

  // D1: K1 (q-proj) || K2 (c_kv split-K partials)
  d1_qproj_ckv<<<dim3(1024), 256, 0, stream>>>(xq_bf, wq_bf, xkv_bf, wkvd_bf,
                                               q_bf, pbuf);

  // D2: K3 (q_lat per-head) || reduce (c_kvb)
  d2_qlat_reduce<<<dim3(1536), 256, 0, stream>>>(q_bf, wkt, qlat_bf, pbuf, c_kvb);

  // K4: fused gather + latent scores + softmax + latent PV (bf16 MFMA)
  attn_mfma<<<dim3(2048), 256, 0, stream>>>(c_kvb, qlat_bf, idx, cw_bf);

  // K5: o_bf[bq,h*64+n] = bf16(cw[bq,h,:] @ W_v[h]^T)  (M=2048,N=64,K=128, z=h)
  gemm_nt_g<<<dim3(1, 32, 16), 256, 0, stream>>>(
      cw_bf, 2048, 128, wv_bf, 128, 8192, nullptr, o_bf, 1024, 64, 128, 1);

  // K6: out = o @ W_out^T  (fp32 out)  (M=2048,N=1024,K=1024)
  gemm_nt_g<<<dim3(16, 32, 1), 256, 0, stream>>>(
      o_bf, 1024, 0, wout_bf, 1024, 0, out, nullptr, 1024, 0, 1024, 0);
}

// Round 9
// 66.047 us; speedup vs baseline: 1.2208x; 1.0729x over previous
//
#include <hip/hip_runtime.h>

// DeepSeek-MLA sparse attention, absorbed formulation, full bf16-MFMA pipeline.
// B=2 NQ=1024 NKV=2048 K=64 D=1024 H=16 LAT=128 HD=64
// Round-9: GEMM inner loop BK=32 -> BK=64, stored as TWO independent BK=32
// sub-tiles (identical slot/swizzle formulas, offset sub*256 slots). Halves
// the per-GEMM count of full vmcnt(0)+barrier drains (round-7 showed making
// drains cheaper fails; this reduces how many there are). Accumulation order
// is bit-identical to round 8 -> absmax must stay exactly 0.0078125.
#define NKVc  2048
#define SCALE 0.125f

typedef unsigned short u16;
typedef __attribute__((ext_vector_type(8))) short short8b;     // 8 bf16 (MFMA frag)
typedef __attribute__((ext_vector_type(8))) unsigned short ushort8;
typedef __attribute__((ext_vector_type(4))) float f32x4;

__device__ __forceinline__ u16 f2bf(float f) {
  unsigned int u = __float_as_uint(f);
  return (u16)((u + 0x7FFFu + ((u >> 16) & 1u)) >> 16);   // RNE
}

// ---------------------------------------------------------------------------
// Mega-conversion: all fp32->bf16 prep in ONE dispatch. Unit = 8 elements.
// ---------------------------------------------------------------------------
__device__ __forceinline__ void conv8(const float* __restrict__ in,
                                      u16* __restrict__ out, int j) {
  float4 f0 = ((const float4*)in)[j * 2];
  float4 f1 = ((const float4*)in)[j * 2 + 1];
  ushort4 a, b;
  a.x = f2bf(f0.x); a.y = f2bf(f0.y); a.z = f2bf(f0.z); a.w = f2bf(f0.w);
  b.x = f2bf(f1.x); b.y = f2bf(f1.y); b.z = f2bf(f1.z); b.w = f2bf(f1.w);
  ((ushort4*)out)[j * 2] = a;
  ((ushort4*)out)[j * 2 + 1] = b;
}

__global__ __launch_bounds__(256)
void megaconv(const float* __restrict__ xq, const float* __restrict__ wq,
              const float* __restrict__ xkv, const float* __restrict__ wkvd,
              const float* __restrict__ wkvu, const float* __restrict__ wout,
              u16* __restrict__ xq_bf, u16* __restrict__ wq_bf,
              u16* __restrict__ xkv_bf, u16* __restrict__ wkvd_bf,
              u16* __restrict__ wv_bf, u16* __restrict__ wout_bf,
              u16* __restrict__ wkt) {
  int i = blockIdx.x * 256 + threadIdx.x;
  if (i < 262144) { conv8(xq, xq_bf, i); return; }
  if (i < 393216) { conv8(wq, wq_bf, i - 262144); return; }
  if (i < 917504) { conv8(xkv, xkv_bf, i - 393216); return; }
  if (i < 933888) { conv8(wkvd, wkvd_bf, i - 917504); return; }
  if (i < 950272) { conv8(wkvu + 131072, wv_bf, i - 933888); return; }
  if (i < 1081344) { conv8(wout, wout_bf, i - 950272); return; }
  {
    int o = (i - 1081344) * 8;          // 8 consecutive hd in one (h,l)
    int hd0 = o & 63;
    int l = (o >> 6) & 127;
    int h = o >> 13;
    const float* src = wkvu + (h * 64 + hd0) * 128 + l;
    ushort8 v;
#pragma unroll
    for (int j = 0; j < 8; ++j) v[j] = f2bf(src[j * 128]);
    *(ushort8*)&wkt[o] = v;
  }
}

// ---------------------------------------------------------------------------
// bf16 MFMA GEMM-NT body (BM=64, BN=64, BK=64, 256 thr / 4 waves 2x2).
// LDS = two proven BK=32 sub-tiles per buffer (slot formulas unchanged from
// the round-6/8 validated code; sub-tile `sub` lives at slot offset sub*256
// and covers global k in [t*64 + sub*32, +32)). 2-phase double buffer, full
// drain per K-step -- 16 drains for K=1024 instead of 32.
// obf (runtime): epilogue writes bf16 to Cb, else fp32 to C.
// ---------------------------------------------------------------------------
__device__ __forceinline__ void gemm_body(
    int bx, int by, int bz,
    const u16* __restrict__ A, int lda, long sAz,
    const u16* __restrict__ B, int ldb, long sBz,
    float* __restrict__ C, u16* __restrict__ Cb,
    int ldc, long sCz, int K, bool obf) {
  A += (size_t)bz * sAz;
  B += (size_t)bz * sBz;
  __shared__ __align__(16) u16 As[2][512 * 8];   // 2 x 8 KB (2 sub-tiles)
  __shared__ __align__(16) u16 Bs[2][512 * 8];   // 2 x 8 KB
  const int tid = threadIdx.x;
  const int w = tid >> 6, lane = tid & 63;
  const int bm = by * 64, bn = bx * 64;
  const int wr = w >> 1, wc = w & 1;

  f32x4 acc[2][2] = {};

  auto stage = [&](int buf, int t) {
#pragma unroll
    for (int sub = 0; sub < 2; ++sub) {
      int s = w * 64 + lane;
      int row = s >> 2;
      int kc = (s & 3) ^ ((row >> 1) & 3);
      int kg = t * 64 + sub * 32 + kc * 8;
      {
        const u16* g = A + (size_t)(bm + row) * lda + kg;
        __builtin_amdgcn_global_load_lds(
            (const __attribute__((address_space(1))) unsigned int*)g,
            (__attribute__((address_space(3))) unsigned int*)&As[buf][(sub * 256 + w * 64) * 8],
            16, 0, 0);
      }
      {
        const u16* g = B + (size_t)(bn + row) * ldb + kg;
        __builtin_amdgcn_global_load_lds(
            (const __attribute__((address_space(1))) unsigned int*)g,
            (__attribute__((address_space(3))) unsigned int*)&Bs[buf][(sub * 256 + w * 64) * 8],
            16, 0, 0);
      }
    }
  };

  auto compute = [&](int buf) {
#pragma unroll
    for (int sub = 0; sub < 2; ++sub) {
      short8b a[2], b[2];
#pragma unroll
      for (int m = 0; m < 2; ++m) {
        int row = wr * 32 + m * 16 + (lane & 15);
        int slot = sub * 256 + row * 4 + ((lane >> 4) ^ ((row >> 1) & 3));
        a[m] = *(const short8b*)&As[buf][slot * 8];
      }
#pragma unroll
      for (int n = 0; n < 2; ++n) {
        int col = wc * 32 + n * 16 + (lane & 15);
        int slot = sub * 256 + col * 4 + ((lane >> 4) ^ ((col >> 1) & 3));
        b[n] = *(const short8b*)&Bs[buf][slot * 8];
      }
#pragma unroll
      for (int m = 0; m < 2; ++m)
#pragma unroll
        for (int n = 0; n < 2; ++n)
          acc[m][n] = __builtin_amdgcn_mfma_f32_16x16x32_bf16(a[m], b[n], acc[m][n], 0, 0, 0);
    }
  };

  stage(0, 0);
  asm volatile("s_waitcnt vmcnt(0)" ::: "memory");
  __syncthreads();
  const int nk = K >> 6;
  for (int t = 0; t < nk; ++t) {
    int cur = t & 1;
    if (t + 1 < nk) stage(cur ^ 1, t + 1);
    compute(cur);
    asm volatile("s_waitcnt vmcnt(0)" ::: "memory");
    __syncthreads();
  }

#pragma unroll
  for (int m = 0; m < 2; ++m) {
    int row0 = bm + wr * 32 + m * 16 + (lane >> 4) * 4;
#pragma unroll
    for (int n = 0; n < 2; ++n) {
      int col = bn + wc * 32 + n * 16 + (lane & 15);
      if (obf) {
        u16* Cz = Cb + (size_t)bz * sCz;
#pragma unroll
        for (int r = 0; r < 4; ++r)
          Cz[(size_t)(row0 + r) * ldc + col] = f2bf(acc[m][n][r]);
      } else {
        float* Cz = C + (size_t)bz * sCz;
#pragma unroll
        for (int r = 0; r < 4; ++r)
          Cz[(size_t)(row0 + r) * ldc + col] = acc[m][n][r];
      }
    }
  }
}

// standalone wrapper (K5, K6)
__global__ __launch_bounds__(256)
void gemm_nt_g(const u16* __restrict__ A, int lda, long sAz,
               const u16* __restrict__ B, int ldb, long sBz,
               float* __restrict__ C, u16* __restrict__ Cb,
               int ldc, long sCz, int K, int obf) {
  gemm_body(blockIdx.x, blockIdx.y, blockIdx.z, A, lda, sAz, B, ldb, sBz,
            C, Cb, ldc, sCz, K, obf != 0);
}

// ---------------------------------------------------------------------------
// D1: K1 || K2 in one dispatch (both depend only on megaconv).
//   blocks [0,512):    K1  q_bf = bf16(x_q @ W_q^T), grid (16,32)
//   blocks [512,1024): K2  pbuf[z] = x_kv @ W_kvd^T partials, grid (2,64,4)
// ---------------------------------------------------------------------------
__global__ __launch_bounds__(256)
void d1_qproj_ckv(const u16* __restrict__ xq_bf, const u16* __restrict__ wq_bf,
                  const u16* __restrict__ xkv_bf, const u16* __restrict__ wkvd_bf,
                  u16* __restrict__ q_bf, float* __restrict__ pbuf) {
  int b = blockIdx.x;
  if (b < 512) {
    gemm_body(b & 15, b >> 4, 0, xq_bf, 1024, 0, wq_bf, 1024, 0,
              nullptr, q_bf, 1024, 0, 1024, true);
  } else {
    int b2 = b - 512;
    gemm_body(b2 & 1, (b2 >> 1) & 63, b2 >> 7, xkv_bf, 1024, 256,
              wkvd_bf, 1024, 256, pbuf, nullptr, 128, (long)4096 * 128,
              256, false);
  }
}

// ---------------------------------------------------------------------------
// D2: K3 || reduce4b in one dispatch (K3 needs q_bf<-D1; reduce needs pbuf<-D1).
//   blocks [0,1024):    K3  qlat_bf[z=h] = bf16(q @ wkt[h]^T), grid (2,32,16)
//   blocks [1024,1536): reduce: c_kvb[i] = bf16(sum_p pbuf[p][i])
// ---------------------------------------------------------------------------
__global__ __launch_bounds__(256)
void d2_qlat_reduce(const u16* __restrict__ q_bf, const u16* __restrict__ wkt,
                    u16* __restrict__ qlat_bf, const float* __restrict__ pbuf,
                    u16* __restrict__ c_kvb) {
  int b = blockIdx.x;
  if (b >= 1024) {
    int i = (b - 1024) * 256 + threadIdx.x;   // n4 = 131072
    const float4* s = (const float4*)pbuf;
    float4 a = s[i], bb = s[i + 131072], c = s[i + 2 * 131072], d = s[i + 3 * 131072];
    ushort4 v;
    v.x = f2bf(a.x + bb.x + c.x + d.x); v.y = f2bf(a.y + bb.y + c.y + d.y);
    v.z = f2bf(a.z + bb.z + c.z + d.z); v.w = f2bf(a.w + bb.w + c.w + d.w);
    ((ushort4*)c_kvb)[i] = v;
    return;
  }
  int bz = b >> 6, r = b & 63;
  gemm_body(r & 1, r >> 1, bz, q_bf, 1024, 64, wkt, 64, 8192,
            nullptr, qlat_bf, 2048, 128, 64, true);
}

// ---------------------------------------------------------------------------
// Fused sparse attention in latent space, bf16 MFMA. One block per (b,q).
// (unchanged -- proven correct)
// ---------------------------------------------------------------------------
__global__ __launch_bounds__(256)
void attn_mfma(const u16* __restrict__ c_kvb,   // (B, 2048, 128) bf16
               const u16* __restrict__ q_latb,  // (BQ, 16, 128) bf16
               const int* __restrict__ indices, // (BQ, 64)
               u16* __restrict__ cw_bf) {       // (BQ, 16, 128) bf16
  __shared__ __align__(16) u16 qls[256 * 8];
  __shared__ __align__(16) u16 csa[1024 * 8];
  __shared__ __align__(16) u16 cst[128 * 72];
  __shared__ __align__(16) u16 pT[16 * 72];
  __shared__ __align__(16) float redmax[64];
  __shared__ __align__(16) float redsum[64];
  __shared__ __align__(16) u16 outst[2048];

  const int tid = threadIdx.x;
  const int w = tid >> 6, lane = tid & 63;
  const int bq = blockIdx.x;
  const int b = bq >> 10;

  {
    int h = tid >> 4, c = tid & 15;
    ushort8 v = *(const ushort8*)(q_latb + (size_t)bq * 2048 + tid * 8);
    *(ushort8*)&qls[(h * 16 + (c ^ h)) * 8] = v;
  }
  {
    int kidx = indices[bq * 64 + lane];
    const u16* src = c_kvb + ((size_t)b * NKVc + kidx) * 128 + w * 32;
    ushort8 v[4];
#pragma unroll
    for (int t = 0; t < 4; ++t) v[t] = *(const ushort8*)(src + t * 8);
#pragma unroll
    for (int t = 0; t < 4; ++t) {
      int c = w * 4 + t;
      *(ushort8*)&csa[(lane * 16 + (c ^ (lane & 15))) * 8] = v[t];
    }
#pragma unroll
    for (int t = 0; t < 4; ++t)
#pragma unroll
      for (int j = 0; j < 8; ++j)
        cst[(w * 32 + t * 8 + j) * 72 + lane] = v[t][j];
  }
  __syncthreads();

  f32x4 sacc = {};
#pragma unroll
  for (int kc = 0; kc < 4; ++kc) {
    int ar = w * 16 + (lane & 15);
    int ac = kc * 4 + (lane >> 4);
    short8b av = *(const short8b*)&csa[(ar * 16 + (ac ^ (ar & 15))) * 8];
    int bh = lane & 15;
    short8b bv = *(const short8b*)&qls[(bh * 16 + (ac ^ bh)) * 8];
    sacc = __builtin_amdgcn_mfma_f32_16x16x32_bf16(av, bv, sacc, 0, 0, 0);
  }
  float s0 = sacc[0] * SCALE, s1 = sacc[1] * SCALE;
  float s2 = sacc[2] * SCALE, s3 = sacc[3] * SCALE;
  float mx = fmaxf(fmaxf(s0, s1), fmaxf(s2, s3));
  mx = fmaxf(mx, __shfl_xor(mx, 16));
  mx = fmaxf(mx, __shfl_xor(mx, 32));
  if (lane < 16) redmax[w * 16 + lane] = mx;
  __syncthreads();
  const int h = lane & 15;
  float m4 = fmaxf(fmaxf(redmax[h], redmax[16 + h]),
                   fmaxf(redmax[32 + h], redmax[48 + h]));
  float p0 = __expf(s0 - m4), p1 = __expf(s1 - m4);
  float p2 = __expf(s2 - m4), p3 = __expf(s3 - m4);
  float sm = p0 + p1 + p2 + p3;
  sm += __shfl_xor(sm, 16);
  sm += __shfl_xor(sm, 32);
  if (lane < 16) redsum[w * 16 + lane] = sm;
  __syncthreads();
  float tot = redsum[h] + redsum[16 + h] + redsum[32 + h] + redsum[48 + h];
  float inv = 1.0f / tot;
  {
    ushort4 pw;
    pw.x = f2bf(p0 * inv); pw.y = f2bf(p1 * inv);
    pw.z = f2bf(p2 * inv); pw.w = f2bf(p3 * inv);
    *(ushort4*)&pT[h * 72 + w * 16 + (lane >> 4) * 4] = pw;
  }
  __syncthreads();

  f32x4 pacc0 = {}, pacc1 = {};
#pragma unroll
  for (int kc = 0; kc < 2; ++kc) {
    short8b pa = *(const short8b*)&pT[(lane & 15) * 72 + kc * 32 + (lane >> 4) * 8];
    int cch = kc * 4 + (lane >> 4);
    int n0 = w * 32 + (lane & 15);
    short8b b0 = *(const short8b*)&cst[n0 * 72 + cch * 8];
    short8b b1 = *(const short8b*)&cst[(n0 + 16) * 72 + cch * 8];
    pacc0 = __builtin_amdgcn_mfma_f32_16x16x32_bf16(pa, b0, pacc0, 0, 0, 0);
    pacc1 = __builtin_amdgcn_mfma_f32_16x16x32_bf16(pa, b1, pacc1, 0, 0, 0);
  }
#pragma unroll
  for (int r = 0; r < 4; ++r) {
    int hh = (lane >> 4) * 4 + r;
    outst[hh * 128 + w * 32 + (lane & 15)] = f2bf(pacc0[r]);
    outst[hh * 128 + w * 32 + 16 + (lane & 15)] = f2bf(pacc1[r]);
  }
  __syncthreads();
  *(ushort8*)(cw_bf + (size_t)bq * 2048 + tid * 8) = *(const ushort8*)&outst[tid * 8];
}

extern "C" void kernel_launch(void* const* d_in, const int* in_sizes, int n_in,
                              void* d_out, int out_size, void* d_ws, size_t ws_size,
                              hipStream_t stream) {
  const float* x_q    = (const float*)d_in[0];
  const float* x_kv   = (const float*)d_in[1];
  const int*   idx    = (const int*)  d_in[2];
  const float* W_q    = (const float*)d_in[3];
  const float* W_kvd  = (const float*)d_in[4];
  const float* W_kvu  = (const float*)d_in[5];
  const float* W_out  = (const float*)d_in[6];
  float* out = (float*)d_out;

  // byte-offset workspace carve; top = 42 MB (proven footprint)
  char* wsb = (char*)d_ws;
  u16* xq_bf   = (u16*)(wsb + 0);                            // 4 MB
  u16* wq_bf   = (u16*)(wsb + (4u << 20));                   // 2 MB
  u16* xkv_bf  = (u16*)(wsb + (6u << 20));                   // 8 MB
  u16* wkvd_bf = (u16*)(wsb + (14u << 20));                  // 256 KB
  u16* wkt     = (u16*)(wsb + (14u << 20) + (256u << 10));   // 256 KB
  u16* wv_bf   = (u16*)(wsb + (14u << 20) + (512u << 10));   // 256 KB
  u16* wout_bf = (u16*)(wsb + (14u << 20) + (768u << 10));   // 2 MB
  u16* q_bf    = (u16*)(wsb + (17u << 20));                  // 4 MB
  u16* c_kvb   = (u16*)(wsb + (21u << 20));                  // 1 MB
  u16* qlat_bf = (u16*)(wsb + (22u << 20));                  // 8 MB
  u16* cw_bf   = (u16*)(wsb + (30u << 20));                  // 8 MB
  u16* o_bf    = (u16*)(wsb + (38u << 20));                  // 4 MB
  float* pbuf  = (float*)(wsb + (30u << 20));                // 8 MB, alias cw (dead pre-attn)

  // C0: all conversions in one dispatch
  megaconv<<<dim3(4288), 256, 0, stream>>>(x_q, W_q, x_kv, W_kvd, W_kvu, W_out,
                                           xq_bf, wq_bf, xkv_bf, wkvd_bf,
                                           wv_bf, wout_bf, wkt);

  // D1: K1 (q-proj) || K2 (c_kv split-K partials)
  d1_qproj_ckv<<<dim3(1024), 256, 0, stream>>>(xq_bf, wq_bf, xkv_bf, wkvd_bf,
                                               q_bf, pbuf);

  // D2: K3 (q_lat per-head) || reduce (c_kvb)
  d2_qlat_reduce<<<dim3(1536), 256, 0, stream>>>(q_bf, wkt, qlat_bf, pbuf, c_kvb);

  // K4: fused gather + latent scores + softmax + latent PV (bf16 MFMA)
  attn_mfma<<<dim3(2048), 256, 0, stream>>>(c_kvb, qlat_bf, idx, cw_bf);

  // K5: o_bf[bq,h*64+n] = bf16(cw[bq,h,:] @ W_v[h]^T)  (M=2048,N=64,K=128, z=h)
  gemm_nt_g<<<dim3(1, 32, 16), 256, 0, stream>>>(
      cw_bf, 2048, 128, wv_bf, 128, 8192, nullptr, o_bf, 1024, 64, 128, 1);

  // K6: out = o @ W_out^T  (fp32 out)  (M=2048,N=1024,K=1024)
  gemm_nt_g<<<dim3(16, 32, 1), 256, 0, stream>>>(
      o_bf, 1024, 0, wout_bf, 1024, 0, out, nullptr, 1024, 0, 1024, 0);
}

// Round 10
// 63.685 us; speedup vs baseline: 1.2661x; 1.0371x over previous
//
#include <hip/hip_runtime.h>

// DeepSeek-MLA sparse attention, absorbed formulation, full bf16-MFMA pipeline.
// B=2 NQ=1024 NKV=2048 K=64 D=1024 H=16 LAT=128 HD=64
// Round-10: (A) split-K removed from K2 -- direct K=1024 GEMM (128 blocks,
// nk=16, same duration as K1's blocks -> D1 is 640 homogeneous co-resident
// blocks); kills 17 MB of partial traffic + the reduce branch in D2.
// (B) NSUB templated: K5/K6 use BK=128 (grid-limited 2/CU before & after, so
// m132's occupancy-cut mechanism can't apply); D1/D2 stay BK=64 / 32 KB LDS
// to preserve residency.
#define NKVc  2048
#define SCALE 0.125f

typedef unsigned short u16;
typedef __attribute__((ext_vector_type(8))) short short8b;     // 8 bf16 (MFMA frag)
typedef __attribute__((ext_vector_type(8))) unsigned short ushort8;
typedef __attribute__((ext_vector_type(4))) float f32x4;

__device__ __forceinline__ u16 f2bf(float f) {
  unsigned int u = __float_as_uint(f);
  return (u16)((u + 0x7FFFu + ((u >> 16) & 1u)) >> 16);   // RNE
}

// ---------------------------------------------------------------------------
// Mega-conversion: all fp32->bf16 prep in ONE dispatch. Unit = 8 elements.
// ---------------------------------------------------------------------------
__device__ __forceinline__ void conv8(const float* __restrict__ in,
                                      u16* __restrict__ out, int j) {
  float4 f0 = ((const float4*)in)[j * 2];
  float4 f1 = ((const float4*)in)[j * 2 + 1];
  ushort4 a, b;
  a.x = f2bf(f0.x); a.y = f2bf(f0.y); a.z = f2bf(f0.z); a.w = f2bf(f0.w);
  b.x = f2bf(f1.x); b.y = f2bf(f1.y); b.z = f2bf(f1.z); b.w = f2bf(f1.w);
  ((ushort4*)out)[j * 2] = a;
  ((ushort4*)out)[j * 2 + 1] = b;
}

__global__ __launch_bounds__(256)
void megaconv(const float* __restrict__ xq, const float* __restrict__ wq,
              const float* __restrict__ xkv, const float* __restrict__ wkvd,
              const float* __restrict__ wkvu, const float* __restrict__ wout,
              u16* __restrict__ xq_bf, u16* __restrict__ wq_bf,
              u16* __restrict__ xkv_bf, u16* __restrict__ wkvd_bf,
              u16* __restrict__ wv_bf, u16* __restrict__ wout_bf,
              u16* __restrict__ wkt) {
  int i = blockIdx.x * 256 + threadIdx.x;
  if (i < 262144) { conv8(xq, xq_bf, i); return; }
  if (i < 393216) { conv8(wq, wq_bf, i - 262144); return; }
  if (i < 917504) { conv8(xkv, xkv_bf, i - 393216); return; }
  if (i < 933888) { conv8(wkvd, wkvd_bf, i - 917504); return; }
  if (i < 950272) { conv8(wkvu + 131072, wv_bf, i - 933888); return; }
  if (i < 1081344) { conv8(wout, wout_bf, i - 950272); return; }
  {
    int o = (i - 1081344) * 8;          // 8 consecutive hd in one (h,l)
    int hd0 = o & 63;
    int l = (o >> 6) & 127;
    int h = o >> 13;
    const float* src = wkvu + (h * 64 + hd0) * 128 + l;
    ushort8 v;
#pragma unroll
    for (int j = 0; j < 8; ++j) v[j] = f2bf(src[j * 128]);
    *(ushort8*)&wkt[o] = v;
  }
}

// ---------------------------------------------------------------------------
// bf16 MFMA GEMM-NT body (BM=64, BN=64, BK=NSUB*32, 256 thr / 4 waves 2x2).
// LDS = NSUB independent proven BK=32 sub-tiles per buffer (slot formulas
// unchanged; sub-tile `sub` at slot offset sub*256, global k in
// [t*NSUB*32 + sub*32, +32)). 2-phase double buffer, full drain per K-step.
// NSUB=2: 32 KB LDS (D1/D2, preserves residency). NSUB=4: 64 KB (K5/K6,
// grid-limited to 2 blocks/CU regardless).
// ---------------------------------------------------------------------------
template<int NSUB>
__device__ __forceinline__ void gemm_body(
    int bx, int by, int bz,
    const u16* __restrict__ A, int lda, long sAz,
    const u16* __restrict__ B, int ldb, long sBz,
    float* __restrict__ C, u16* __restrict__ Cb,
    int ldc, long sCz, int K, bool obf) {
  A += (size_t)bz * sAz;
  B += (size_t)bz * sBz;
  __shared__ __align__(16) u16 As[2][NSUB * 256 * 8];
  __shared__ __align__(16) u16 Bs[2][NSUB * 256 * 8];
  const int tid = threadIdx.x;
  const int w = tid >> 6, lane = tid & 63;
  const int bm = by * 64, bn = bx * 64;
  const int wr = w >> 1, wc = w & 1;

  f32x4 acc[2][2] = {};

  auto stage = [&](int buf, int t) {
#pragma unroll
    for (int sub = 0; sub < NSUB; ++sub) {
      int s = w * 64 + lane;
      int row = s >> 2;
      int kc = (s & 3) ^ ((row >> 1) & 3);
      int kg = t * (NSUB * 32) + sub * 32 + kc * 8;
      {
        const u16* g = A + (size_t)(bm + row) * lda + kg;
        __builtin_amdgcn_global_load_lds(
            (const __attribute__((address_space(1))) unsigned int*)g,
            (__attribute__((address_space(3))) unsigned int*)&As[buf][(sub * 256 + w * 64) * 8],
            16, 0, 0);
      }
      {
        const u16* g = B + (size_t)(bn + row) * ldb + kg;
        __builtin_amdgcn_global_load_lds(
            (const __attribute__((address_space(1))) unsigned int*)g,
            (__attribute__((address_space(3))) unsigned int*)&Bs[buf][(sub * 256 + w * 64) * 8],
            16, 0, 0);
      }
    }
  };

  auto compute = [&](int buf) {
#pragma unroll
    for (int sub = 0; sub < NSUB; ++sub) {
      short8b a[2], b[2];
#pragma unroll
      for (int m = 0; m < 2; ++m) {
        int row = wr * 32 + m * 16 + (lane & 15);
        int slot = sub * 256 + row * 4 + ((lane >> 4) ^ ((row >> 1) & 3));
        a[m] = *(const short8b*)&As[buf][slot * 8];
      }
#pragma unroll
      for (int n = 0; n < 2; ++n) {
        int col = wc * 32 + n * 16 + (lane & 15);
        int slot = sub * 256 + col * 4 + ((lane >> 4) ^ ((col >> 1) & 3));
        b[n] = *(const short8b*)&Bs[buf][slot * 8];
      }
#pragma unroll
      for (int m = 0; m < 2; ++m)
#pragma unroll
        for (int n = 0; n < 2; ++n)
          acc[m][n] = __builtin_amdgcn_mfma_f32_16x16x32_bf16(a[m], b[n], acc[m][n], 0, 0, 0);
    }
  };

  stage(0, 0);
  asm volatile("s_waitcnt vmcnt(0)" ::: "memory");
  __syncthreads();
  const int nk = K / (NSUB * 32);
  for (int t = 0; t < nk; ++t) {
    int cur = t & 1;
    if (t + 1 < nk) stage(cur ^ 1, t + 1);
    compute(cur);
    asm volatile("s_waitcnt vmcnt(0)" ::: "memory");
    __syncthreads();
  }

#pragma unroll
  for (int m = 0; m < 2; ++m) {
    int row0 = bm + wr * 32 + m * 16 + (lane >> 4) * 4;
#pragma unroll
    for (int n = 0; n < 2; ++n) {
      int col = bn + wc * 32 + n * 16 + (lane & 15);
      if (obf) {
        u16* Cz = Cb + (size_t)bz * sCz;
#pragma unroll
        for (int r = 0; r < 4; ++r)
          Cz[(size_t)(row0 + r) * ldc + col] = f2bf(acc[m][n][r]);
      } else {
        float* Cz = C + (size_t)bz * sCz;
#pragma unroll
        for (int r = 0; r < 4; ++r)
          Cz[(size_t)(row0 + r) * ldc + col] = acc[m][n][r];
      }
    }
  }
}

// standalone wrapper, BK=128 (K5, K6)
__global__ __launch_bounds__(256)
void gemm_nt_g4(const u16* __restrict__ A, int lda, long sAz,
                const u16* __restrict__ B, int ldb, long sBz,
                float* __restrict__ C, u16* __restrict__ Cb,
                int ldc, long sCz, int K, int obf) {
  gemm_body<4>(blockIdx.x, blockIdx.y, blockIdx.z, A, lda, sAz, B, ldb, sBz,
               C, Cb, ldc, sCz, K, obf != 0);
}

// ---------------------------------------------------------------------------
// D1: K1 || K2-direct in one dispatch (both depend only on megaconv).
//   blocks [0,512):   K1  q_bf = bf16(x_q @ W_q^T), grid (16,32), nk=16
//   blocks [512,640): K2  c_kvb = bf16(x_kv @ W_kvd^T), grid (2,64), nk=16
// 640 homogeneous blocks (same nk), 32 KB LDS -> all co-resident.
// ---------------------------------------------------------------------------
__global__ __launch_bounds__(256)
void d1_qproj_ckv(const u16* __restrict__ xq_bf, const u16* __restrict__ wq_bf,
                  const u16* __restrict__ xkv_bf, const u16* __restrict__ wkvd_bf,
                  u16* __restrict__ q_bf, u16* __restrict__ c_kvb) {
  int b = blockIdx.x;
  if (b < 512) {
    gemm_body<2>(b & 15, b >> 4, 0, xq_bf, 1024, 0, wq_bf, 1024, 0,
                 nullptr, q_bf, 1024, 0, 1024, true);
  } else {
    int b2 = b - 512;
    gemm_body<2>(b2 & 1, b2 >> 1, 0, xkv_bf, 1024, 0, wkvd_bf, 1024, 0,
                 nullptr, c_kvb, 128, 0, 1024, true);
  }
}

// ---------------------------------------------------------------------------
// D2: K3 only (reduce eliminated).  qlat_bf[z=h] = bf16(q @ wkt[h]^T)
// grid flattened: 1024 blocks = (2,32,16)
// ---------------------------------------------------------------------------
__global__ __launch_bounds__(256)
void d2_qlat(const u16* __restrict__ q_bf, const u16* __restrict__ wkt,
             u16* __restrict__ qlat_bf) {
  int b = blockIdx.x;
  int bz = b >> 6, r = b & 63;
  gemm_body<2>(r & 1, r >> 1, bz, q_bf, 1024, 64, wkt, 64, 8192,
               nullptr, qlat_bf, 2048, 128, 64, true);
}

// ---------------------------------------------------------------------------
// Fused sparse attention in latent space, bf16 MFMA. One block per (b,q).
// (unchanged -- proven correct)
// ---------------------------------------------------------------------------
__global__ __launch_bounds__(256)
void attn_mfma(const u16* __restrict__ c_kvb,   // (B, 2048, 128) bf16
               const u16* __restrict__ q_latb,  // (BQ, 16, 128) bf16
               const int* __restrict__ indices, // (BQ, 64)
               u16* __restrict__ cw_bf) {       // (BQ, 16, 128) bf16
  __shared__ __align__(16) u16 qls[256 * 8];
  __shared__ __align__(16) u16 csa[1024 * 8];
  __shared__ __align__(16) u16 cst[128 * 72];
  __shared__ __align__(16) u16 pT[16 * 72];
  __shared__ __align__(16) float redmax[64];
  __shared__ __align__(16) float redsum[64];
  __shared__ __align__(16) u16 outst[2048];

  const int tid = threadIdx.x;
  const int w = tid >> 6, lane = tid & 63;
  const int bq = blockIdx.x;
  const int b = bq >> 10;

  {
    int h = tid >> 4, c = tid & 15;
    ushort8 v = *(const ushort8*)(q_latb + (size_t)bq * 2048 + tid * 8);
    *(ushort8*)&qls[(h * 16 + (c ^ h)) * 8] = v;
  }
  {
    int kidx = indices[bq * 64 + lane];
    const u16* src = c_kvb + ((size_t)b * NKVc + kidx) * 128 + w * 32;
    ushort8 v[4];
#pragma unroll
    for (int t = 0; t < 4; ++t) v[t] = *(const ushort8*)(src + t * 8);
#pragma unroll
    for (int t = 0; t < 4; ++t) {
      int c = w * 4 + t;
      *(ushort8*)&csa[(lane * 16 + (c ^ (lane & 15))) * 8] = v[t];
    }
#pragma unroll
    for (int t = 0; t < 4; ++t)
#pragma unroll
      for (int j = 0; j < 8; ++j)
        cst[(w * 32 + t * 8 + j) * 72 + lane] = v[t][j];
  }
  __syncthreads();

  f32x4 sacc = {};
#pragma unroll
  for (int kc = 0; kc < 4; ++kc) {
    int ar = w * 16 + (lane & 15);
    int ac = kc * 4 + (lane >> 4);
    short8b av = *(const short8b*)&csa[(ar * 16 + (ac ^ (ar & 15))) * 8];
    int bh = lane & 15;
    short8b bv = *(const short8b*)&qls[(bh * 16 + (ac ^ bh)) * 8];
    sacc = __builtin_amdgcn_mfma_f32_16x16x32_bf16(av, bv, sacc, 0, 0, 0);
  }
  float s0 = sacc[0] * SCALE, s1 = sacc[1] * SCALE;
  float s2 = sacc[2] * SCALE, s3 = sacc[3] * SCALE;
  float mx = fmaxf(fmaxf(s0, s1), fmaxf(s2, s3));
  mx = fmaxf(mx, __shfl_xor(mx, 16));
  mx = fmaxf(mx, __shfl_xor(mx, 32));
  if (lane < 16) redmax[w * 16 + lane] = mx;
  __syncthreads();
  const int h = lane & 15;
  float m4 = fmaxf(fmaxf(redmax[h], redmax[16 + h]),
                   fmaxf(redmax[32 + h], redmax[48 + h]));
  float p0 = __expf(s0 - m4), p1 = __expf(s1 - m4);
  float p2 = __expf(s2 - m4), p3 = __expf(s3 - m4);
  float sm = p0 + p1 + p2 + p3;
  sm += __shfl_xor(sm, 16);
  sm += __shfl_xor(sm, 32);
  if (lane < 16) redsum[w * 16 + lane] = sm;
  __syncthreads();
  float tot = redsum[h] + redsum[16 + h] + redsum[32 + h] + redsum[48 + h];
  float inv = 1.0f / tot;
  {
    ushort4 pw;
    pw.x = f2bf(p0 * inv); pw.y = f2bf(p1 * inv);
    pw.z = f2bf(p2 * inv); pw.w = f2bf(p3 * inv);
    *(ushort4*)&pT[h * 72 + w * 16 + (lane >> 4) * 4] = pw;
  }
  __syncthreads();

  f32x4 pacc0 = {}, pacc1 = {};
#pragma unroll
  for (int kc = 0; kc < 2; ++kc) {
    short8b pa = *(const short8b*)&pT[(lane & 15) * 72 + kc * 32 + (lane >> 4) * 8];
    int cch = kc * 4 + (lane >> 4);
    int n0 = w * 32 + (lane & 15);
    short8b b0 = *(const short8b*)&cst[n0 * 72 + cch * 8];
    short8b b1 = *(const short8b*)&cst[(n0 + 16) * 72 + cch * 8];
    pacc0 = __builtin_amdgcn_mfma_f32_16x16x32_bf16(pa, b0, pacc0, 0, 0, 0);
    pacc1 = __builtin_amdgcn_mfma_f32_16x16x32_bf16(pa, b1, pacc1, 0, 0, 0);
  }
#pragma unroll
  for (int r = 0; r < 4; ++r) {
    int hh = (lane >> 4) * 4 + r;
    outst[hh * 128 + w * 32 + (lane & 15)] = f2bf(pacc0[r]);
    outst[hh * 128 + w * 32 + 16 + (lane & 15)] = f2bf(pacc1[r]);
  }
  __syncthreads();
  *(ushort8*)(cw_bf + (size_t)bq * 2048 + tid * 8) = *(const ushort8*)&outst[tid * 8];
}

extern "C" void kernel_launch(void* const* d_in, const int* in_sizes, int n_in,
                              void* d_out, int out_size, void* d_ws, size_t ws_size,
                              hipStream_t stream) {
  const float* x_q    = (const float*)d_in[0];
  const float* x_kv   = (const float*)d_in[1];
  const int*   idx    = (const int*)  d_in[2];
  const float* W_q    = (const float*)d_in[3];
  const float* W_kvd  = (const float*)d_in[4];
  const float* W_kvu  = (const float*)d_in[5];
  const float* W_out  = (const float*)d_in[6];
  float* out = (float*)d_out;

  // byte-offset workspace carve; top = 42 MB (proven footprint). pbuf gone.
  char* wsb = (char*)d_ws;
  u16* xq_bf   = (u16*)(wsb + 0);                            // 4 MB
  u16* wq_bf   = (u16*)(wsb + (4u << 20));                   // 2 MB
  u16* xkv_bf  = (u16*)(wsb + (6u << 20));                   // 8 MB
  u16* wkvd_bf = (u16*)(wsb + (14u << 20));                  // 256 KB
  u16* wkt     = (u16*)(wsb + (14u << 20) + (256u << 10));   // 256 KB
  u16* wv_bf   = (u16*)(wsb + (14u << 20) + (512u << 10));   // 256 KB
  u16* wout_bf = (u16*)(wsb + (14u << 20) + (768u << 10));   // 2 MB
  u16* q_bf    = (u16*)(wsb + (17u << 20));                  // 4 MB
  u16* c_kvb   = (u16*)(wsb + (21u << 20));                  // 1 MB
  u16* qlat_bf = (u16*)(wsb + (22u << 20));                  // 8 MB
  u16* cw_bf   = (u16*)(wsb + (30u << 20));                  // 8 MB
  u16* o_bf    = (u16*)(wsb + (38u << 20));                  // 4 MB

  // C0: all conversions in one dispatch
  megaconv<<<dim3(4288), 256, 0, stream>>>(x_q, W_q, x_kv, W_kvd, W_kvu, W_out,
                                           xq_bf, wq_bf, xkv_bf, wkvd_bf,
                                           wv_bf, wout_bf, wkt);

  // D1: K1 (q-proj, 512 blocks) || K2-direct (c_kvb, 128 blocks), nk=16 both
  d1_qproj_ckv<<<dim3(640), 256, 0, stream>>>(xq_bf, wq_bf, xkv_bf, wkvd_bf,
                                              q_bf, c_kvb);

  // D2: K3 (q_lat per-head), 1024 blocks
  d2_qlat<<<dim3(1024), 256, 0, stream>>>(q_bf, wkt, qlat_bf);

  // K4: fused gather + latent scores + softmax + latent PV (bf16 MFMA)
  attn_mfma<<<dim3(2048), 256, 0, stream>>>(c_kvb, qlat_bf, idx, cw_bf);

  // K5: o_bf[bq,h*64+n] = bf16(cw[bq,h,:] @ W_v[h]^T)  (BK=128, nk=1)
  gemm_nt_g4<<<dim3(1, 32, 16), 256, 0, stream>>>(
      cw_bf, 2048, 128, wv_bf, 128, 8192, nullptr, o_bf, 1024, 64, 128, 1);

  // K6: out = o @ W_out^T  (fp32 out, BK=128, nk=8)
  gemm_nt_g4<<<dim3(16, 32, 1), 256, 0, stream>>>(
      o_bf, 1024, 0, wout_bf, 1024, 0, out, nullptr, 1024, 0, 1024, 0);
}

// Round 11
// 59.245 us; speedup vs baseline: 1.3610x; 1.0750x over previous
//
#include <hip/hip_runtime.h>

// DeepSeek-MLA sparse attention, absorbed formulation, full bf16-MFMA pipeline.
// B=2 NQ=1024 NKV=2048 K=64 D=1024 H=16 LAT=128 HD=64
// Round-11: K3 fused into K1's registers (K1 block (bx,by) holds exactly the
// per-head q-subblock K3's tile (by,h=bx) needs). After K1's K-loop: acc ->
// bf16 q-tile in LDS (chunk-XOR swizzle), wkt[h] staged via pre-swizzled-src
// global_load_lds, 16 MFMAs/wave, write qlat directly. D2 dispatch + q_bf
// roundtrip eliminated. Same values, same MFMA order as standalone K3 ->
// absmax must stay exactly 0.0078125 (canary). 5 dispatches total.
#define NKVc  2048
#define SCALE 0.125f

typedef unsigned short u16;
typedef __attribute__((ext_vector_type(8))) short short8b;     // 8 bf16 (MFMA frag)
typedef __attribute__((ext_vector_type(8))) unsigned short ushort8;
typedef __attribute__((ext_vector_type(4))) float f32x4;

__device__ __forceinline__ u16 f2bf(float f) {
  unsigned int u = __float_as_uint(f);
  return (u16)((u + 0x7FFFu + ((u >> 16) & 1u)) >> 16);   // RNE
}

#define GLOAD16(gp, lp) \
  __builtin_amdgcn_global_load_lds( \
      (const __attribute__((address_space(1))) unsigned int*)(gp), \
      (__attribute__((address_space(3))) unsigned int*)(lp), 16, 0, 0)

// ---------------------------------------------------------------------------
// Mega-conversion: all fp32->bf16 prep in ONE dispatch. Unit = 8 elements.
// ---------------------------------------------------------------------------
__device__ __forceinline__ void conv8(const float* __restrict__ in,
                                      u16* __restrict__ out, int j) {
  float4 f0 = ((const float4*)in)[j * 2];
  float4 f1 = ((const float4*)in)[j * 2 + 1];
  ushort4 a, b;
  a.x = f2bf(f0.x); a.y = f2bf(f0.y); a.z = f2bf(f0.z); a.w = f2bf(f0.w);
  b.x = f2bf(f1.x); b.y = f2bf(f1.y); b.z = f2bf(f1.z); b.w = f2bf(f1.w);
  ((ushort4*)out)[j * 2] = a;
  ((ushort4*)out)[j * 2 + 1] = b;
}

__global__ __launch_bounds__(256)
void megaconv(const float* __restrict__ xq, const float* __restrict__ wq,
              const float* __restrict__ xkv, const float* __restrict__ wkvd,
              const float* __restrict__ wkvu, const float* __restrict__ wout,
              u16* __restrict__ xq_bf, u16* __restrict__ wq_bf,
              u16* __restrict__ xkv_bf, u16* __restrict__ wkvd_bf,
              u16* __restrict__ wv_bf, u16* __restrict__ wout_bf,
              u16* __restrict__ wkt) {
  int i = blockIdx.x * 256 + threadIdx.x;
  if (i < 262144) { conv8(xq, xq_bf, i); return; }
  if (i < 393216) { conv8(wq, wq_bf, i - 262144); return; }
  if (i < 917504) { conv8(xkv, xkv_bf, i - 393216); return; }
  if (i < 933888) { conv8(wkvd, wkvd_bf, i - 917504); return; }
  if (i < 950272) { conv8(wkvu + 131072, wv_bf, i - 933888); return; }
  if (i < 1081344) { conv8(wout, wout_bf, i - 950272); return; }
  {
    int o = (i - 1081344) * 8;          // 8 consecutive hd in one (h,l)
    int hd0 = o & 63;
    int l = (o >> 6) & 127;
    int h = o >> 13;
    const float* src = wkvu + (h * 64 + hd0) * 128 + l;
    ushort8 v;
#pragma unroll
    for (int j = 0; j < 8; ++j) v[j] = f2bf(src[j * 128]);
    *(ushort8*)&wkt[o] = v;
  }
}

// ---------------------------------------------------------------------------
// GEMM-NT core (BM=64, BN=64, BK=NSUB*32, 4 waves 2x2), caller-owned LDS.
// As/Bs: flat [2][NSUB*256*8] u16. 2-phase double buffer, full drain per step
// (proven round-6..10 structure). Leaves acc in caller registers.
// ---------------------------------------------------------------------------
template<int NSUB>
__device__ __forceinline__ void gemm_loop(
    u16* As, u16* Bs, int bm, int bn,
    const u16* __restrict__ A, int lda,
    const u16* __restrict__ B, int ldb, int K, f32x4 (&acc)[2][2]) {
  const int tid = threadIdx.x;
  const int w = tid >> 6, lane = tid & 63;
  const int wr = w >> 1, wc = w & 1;
  constexpr int BUF = NSUB * 256 * 8;

  auto stage = [&](int buf, int t) {
#pragma unroll
    for (int sub = 0; sub < NSUB; ++sub) {
      int s = w * 64 + lane;
      int row = s >> 2;
      int kc = (s & 3) ^ ((row >> 1) & 3);
      int kg = t * (NSUB * 32) + sub * 32 + kc * 8;
      GLOAD16(A + (size_t)(bm + row) * lda + kg,
              As + buf * BUF + (sub * 256 + w * 64) * 8);
      GLOAD16(B + (size_t)(bn + row) * ldb + kg,
              Bs + buf * BUF + (sub * 256 + w * 64) * 8);
    }
  };

  auto compute = [&](int buf) {
#pragma unroll
    for (int sub = 0; sub < NSUB; ++sub) {
      short8b a[2], b[2];
#pragma unroll
      for (int m = 0; m < 2; ++m) {
        int row = wr * 32 + m * 16 + (lane & 15);
        int slot = sub * 256 + row * 4 + ((lane >> 4) ^ ((row >> 1) & 3));
        a[m] = *(const short8b*)&As[buf * BUF + slot * 8];
      }
#pragma unroll
      for (int n = 0; n < 2; ++n) {
        int col = wc * 32 + n * 16 + (lane & 15);
        int slot = sub * 256 + col * 4 + ((lane >> 4) ^ ((col >> 1) & 3));
        b[n] = *(const short8b*)&Bs[buf * BUF + slot * 8];
      }
#pragma unroll
      for (int m = 0; m < 2; ++m)
#pragma unroll
        for (int n = 0; n < 2; ++n)
          acc[m][n] = __builtin_amdgcn_mfma_f32_16x16x32_bf16(a[m], b[n], acc[m][n], 0, 0, 0);
    }
  };

  stage(0, 0);
  asm volatile("s_waitcnt vmcnt(0)" ::: "memory");
  __syncthreads();
  const int nk = K / (NSUB * 32);
  for (int t = 0; t < nk; ++t) {
    int cur = t & 1;
    if (t + 1 < nk) stage(cur ^ 1, t + 1);
    compute(cur);
    asm volatile("s_waitcnt vmcnt(0)" ::: "memory");
    __syncthreads();
  }
}

__device__ __forceinline__ void gemm_epi(
    f32x4 (&acc)[2][2], int bm, int bn,
    float* __restrict__ C, u16* __restrict__ Cb, int ldc, bool obf) {
  const int lane = threadIdx.x & 63;
  const int w = threadIdx.x >> 6;
  const int wr = w >> 1, wc = w & 1;
#pragma unroll
  for (int m = 0; m < 2; ++m) {
    int row0 = bm + wr * 32 + m * 16 + (lane >> 4) * 4;
#pragma unroll
    for (int n = 0; n < 2; ++n) {
      int col = bn + wc * 32 + n * 16 + (lane & 15);
      if (obf) {
#pragma unroll
        for (int r = 0; r < 4; ++r)
          Cb[(size_t)(row0 + r) * ldc + col] = f2bf(acc[m][n][r]);
      } else {
#pragma unroll
        for (int r = 0; r < 4; ++r)
          C[(size_t)(row0 + r) * ldc + col] = acc[m][n][r];
      }
    }
  }
}

// standalone wrapper, BK=128 (K5, K6)
__global__ __launch_bounds__(256)
void gemm_nt_g4(const u16* __restrict__ A, int lda, long sAz,
                const u16* __restrict__ B, int ldb, long sBz,
                float* __restrict__ C, u16* __restrict__ Cb,
                int ldc, long sCz, int K, int obf) {
  __shared__ __align__(16) u16 As[2 * 1024 * 8];
  __shared__ __align__(16) u16 Bs[2 * 1024 * 8];
  f32x4 acc[2][2] = {};
  gemm_loop<4>(As, Bs, blockIdx.y * 64, blockIdx.x * 64,
               A + (size_t)blockIdx.z * sAz, lda,
               B + (size_t)blockIdx.z * sBz, ldb, K, acc);
  gemm_epi(acc, blockIdx.y * 64, blockIdx.x * 64,
           C ? C + (size_t)blockIdx.z * sCz : nullptr,
           Cb ? Cb + (size_t)blockIdx.z * sCz : nullptr, ldc, obf != 0);
}

// ---------------------------------------------------------------------------
// D1: [0,512)   K1+K3 fused: q-subblock in regs -> qlat[*, h=bx, :] directly
//     [512,640) K2: c_kvb = bf16(x_kv @ W_kvd^T), K=1024
// One shared 32 KB LDS allocation for both paths.
// ---------------------------------------------------------------------------
__global__ __launch_bounds__(256)
void d1_fused(const u16* __restrict__ xq_bf, const u16* __restrict__ wq_bf,
              const u16* __restrict__ xkv_bf, const u16* __restrict__ wkvd_bf,
              const u16* __restrict__ wkt, u16* __restrict__ qlat_bf,
              u16* __restrict__ c_kvb) {
  __shared__ __align__(16) u16 As[2 * 512 * 8];   // 16 KB
  __shared__ __align__(16) u16 Bs[2 * 512 * 8];   // 16 KB
  const int b = blockIdx.x;
  const int tid = threadIdx.x;
  const int w = tid >> 6, lane = tid & 63;
  const int wr = w >> 1, wc = w & 1;
  f32x4 acc[2][2] = {};

  if (b >= 512) {   // K2 path
    int b2 = b - 512;
    int bm = (b2 >> 1) * 64, bn = (b2 & 1) * 64;
    gemm_loop<2>(As, Bs, bm, bn, xkv_bf, 1024, wkvd_bf, 1024, 1024, acc);
    gemm_epi(acc, bm, bn, nullptr, c_kvb, 128, true);
    return;
  }

  // --- K1 phase: q_sub = x_q[by-rows] @ W_q[h-rows]^T (64x64, head h=bx) ---
  const int h = b & 15, bm = (b >> 4) * 64;
  gemm_loop<2>(As, Bs, bm, h * 64, xq_bf, 1024, wq_bf, 1024, 1024, acc);
  // loop ended with full drain + barrier -> As/Bs free for reuse.

  // --- K3 phase: qlat[bm-rows][h][l] = q_sub @ wkt[h]^T  (M=64,N=128,K=64) --
  // Stage wkt[h] (128 l x 64 hd) into Bs: linear dest slot (l,c), source
  // chunk pre-swizzled (c ^ (l&7)) -- read-side applies the same XOR.
#pragma unroll
  for (int i = 0; i < 4; ++i) {
    int s = (w * 4 + i) * 64 + lane;      // 0..1023
    int l = s >> 3, c = s & 7;
    GLOAD16(wkt + h * 8192 + l * 64 + ((c ^ (l & 7)) * 8), Bs + s * 8);
  }
  // Write acc as bf16 q-tile into As: row-stride 64 u16, chunk-XOR swizzle.
#pragma unroll
  for (int mm = 0; mm < 2; ++mm)
#pragma unroll
    for (int nn = 0; nn < 2; ++nn) {
      int hd = wc * 32 + nn * 16 + (lane & 15);
      int c = hd >> 3;
#pragma unroll
      for (int rr = 0; rr < 4; ++rr) {
        int row = wr * 32 + mm * 16 + (lane >> 4) * 4 + rr;
        As[row * 64 + ((c ^ (row & 7)) * 8) + (hd & 7)] = f2bf(acc[mm][nn][rr]);
      }
    }
  asm volatile("s_waitcnt vmcnt(0)" ::: "memory");
  __syncthreads();

  // 16 MFMAs/wave: wave (wr,wc) -> rows wr*32 (2 tiles), l = wc*64 (4 tiles)
  f32x4 acc2[2][4] = {};
#pragma unroll
  for (int ks = 0; ks < 2; ++ks) {
    short8b af[2], bv[4];
#pragma unroll
    for (int mm = 0; mm < 2; ++mm) {
      int row = wr * 32 + mm * 16 + (lane & 15);
      int ch = ks * 4 + (lane >> 4);
      af[mm] = *(const short8b*)&As[row * 64 + ((ch ^ (row & 7)) * 8)];
    }
#pragma unroll
    for (int nf = 0; nf < 4; ++nf) {
      int l = wc * 64 + nf * 16 + (lane & 15);
      int ch = ks * 4 + (lane >> 4);
      bv[nf] = *(const short8b*)&Bs[(l * 8 + (ch ^ (l & 7))) * 8];
    }
#pragma unroll
    for (int mm = 0; mm < 2; ++mm)
#pragma unroll
      for (int nf = 0; nf < 4; ++nf)
        acc2[mm][nf] = __builtin_amdgcn_mfma_f32_16x16x32_bf16(af[mm], bv[nf], acc2[mm][nf], 0, 0, 0);
  }
  // epilogue: qlat (BQ, 16, 128) bf16
#pragma unroll
  for (int mm = 0; mm < 2; ++mm) {
    int row0 = bm + wr * 32 + mm * 16 + (lane >> 4) * 4;
#pragma unroll
    for (int nf = 0; nf < 4; ++nf) {
      int l = wc * 64 + nf * 16 + (lane & 15);
#pragma unroll
      for (int r = 0; r < 4; ++r)
        qlat_bf[(size_t)(row0 + r) * 2048 + h * 128 + l] = f2bf(acc2[mm][nf][r]);
    }
  }
}

// ---------------------------------------------------------------------------
// Fused sparse attention in latent space, bf16 MFMA. One block per (b,q).
// (unchanged -- proven correct)
// ---------------------------------------------------------------------------
__global__ __launch_bounds__(256)
void attn_mfma(const u16* __restrict__ c_kvb,   // (B, 2048, 128) bf16
               const u16* __restrict__ q_latb,  // (BQ, 16, 128) bf16
               const int* __restrict__ indices, // (BQ, 64)
               u16* __restrict__ cw_bf) {       // (BQ, 16, 128) bf16
  __shared__ __align__(16) u16 qls[256 * 8];
  __shared__ __align__(16) u16 csa[1024 * 8];
  __shared__ __align__(16) u16 cst[128 * 72];
  __shared__ __align__(16) u16 pT[16 * 72];
  __shared__ __align__(16) float redmax[64];
  __shared__ __align__(16) float redsum[64];
  __shared__ __align__(16) u16 outst[2048];

  const int tid = threadIdx.x;
  const int w = tid >> 6, lane = tid & 63;
  const int bq = blockIdx.x;
  const int b = bq >> 10;

  {
    int h = tid >> 4, c = tid & 15;
    ushort8 v = *(const ushort8*)(q_latb + (size_t)bq * 2048 + tid * 8);
    *(ushort8*)&qls[(h * 16 + (c ^ h)) * 8] = v;
  }
  {
    int kidx = indices[bq * 64 + lane];
    const u16* src = c_kvb + ((size_t)b * NKVc + kidx) * 128 + w * 32;
    ushort8 v[4];
#pragma unroll
    for (int t = 0; t < 4; ++t) v[t] = *(const ushort8*)(src + t * 8);
#pragma unroll
    for (int t = 0; t < 4; ++t) {
      int c = w * 4 + t;
      *(ushort8*)&csa[(lane * 16 + (c ^ (lane & 15))) * 8] = v[t];
    }
#pragma unroll
    for (int t = 0; t < 4; ++t)
#pragma unroll
      for (int j = 0; j < 8; ++j)
        cst[(w * 32 + t * 8 + j) * 72 + lane] = v[t][j];
  }
  __syncthreads();

  f32x4 sacc = {};
#pragma unroll
  for (int kc = 0; kc < 4; ++kc) {
    int ar = w * 16 + (lane & 15);
    int ac = kc * 4 + (lane >> 4);
    short8b av = *(const short8b*)&csa[(ar * 16 + (ac ^ (ar & 15))) * 8];
    int bh = lane & 15;
    short8b bv = *(const short8b*)&qls[(bh * 16 + (ac ^ bh)) * 8];
    sacc = __builtin_amdgcn_mfma_f32_16x16x32_bf16(av, bv, sacc, 0, 0, 0);
  }
  float s0 = sacc[0] * SCALE, s1 = sacc[1] * SCALE;
  float s2 = sacc[2] * SCALE, s3 = sacc[3] * SCALE;
  float mx = fmaxf(fmaxf(s0, s1), fmaxf(s2, s3));
  mx = fmaxf(mx, __shfl_xor(mx, 16));
  mx = fmaxf(mx, __shfl_xor(mx, 32));
  if (lane < 16) redmax[w * 16 + lane] = mx;
  __syncthreads();
  const int h = lane & 15;
  float m4 = fmaxf(fmaxf(redmax[h], redmax[16 + h]),
                   fmaxf(redmax[32 + h], redmax[48 + h]));
  float p0 = __expf(s0 - m4), p1 = __expf(s1 - m4);
  float p2 = __expf(s2 - m4), p3 = __expf(s3 - m4);
  float sm = p0 + p1 + p2 + p3;
  sm += __shfl_xor(sm, 16);
  sm += __shfl_xor(sm, 32);
  if (lane < 16) redsum[w * 16 + lane] = sm;
  __syncthreads();
  float tot = redsum[h] + redsum[16 + h] + redsum[32 + h] + redsum[48 + h];
  float inv = 1.0f / tot;
  {
    ushort4 pw;
    pw.x = f2bf(p0 * inv); pw.y = f2bf(p1 * inv);
    pw.z = f2bf(p2 * inv); pw.w = f2bf(p3 * inv);
    *(ushort4*)&pT[h * 72 + w * 16 + (lane >> 4) * 4] = pw;
  }
  __syncthreads();

  f32x4 pacc0 = {}, pacc1 = {};
#pragma unroll
  for (int kc = 0; kc < 2; ++kc) {
    short8b pa = *(const short8b*)&pT[(lane & 15) * 72 + kc * 32 + (lane >> 4) * 8];
    int cch = kc * 4 + (lane >> 4);
    int n0 = w * 32 + (lane & 15);
    short8b b0 = *(const short8b*)&cst[n0 * 72 + cch * 8];
    short8b b1 = *(const short8b*)&cst[(n0 + 16) * 72 + cch * 8];
    pacc0 = __builtin_amdgcn_mfma_f32_16x16x32_bf16(pa, b0, pacc0, 0, 0, 0);
    pacc1 = __builtin_amdgcn_mfma_f32_16x16x32_bf16(pa, b1, pacc1, 0, 0, 0);
  }
#pragma unroll
  for (int r = 0; r < 4; ++r) {
    int hh = (lane >> 4) * 4 + r;
    outst[hh * 128 + w * 32 + (lane & 15)] = f2bf(pacc0[r]);
    outst[hh * 128 + w * 32 + 16 + (lane & 15)] = f2bf(pacc1[r]);
  }
  __syncthreads();
  *(ushort8*)(cw_bf + (size_t)bq * 2048 + tid * 8) = *(const ushort8*)&outst[tid * 8];
}

extern "C" void kernel_launch(void* const* d_in, const int* in_sizes, int n_in,
                              void* d_out, int out_size, void* d_ws, size_t ws_size,
                              hipStream_t stream) {
  const float* x_q    = (const float*)d_in[0];
  const float* x_kv   = (const float*)d_in[1];
  const int*   idx    = (const int*)  d_in[2];
  const float* W_q    = (const float*)d_in[3];
  const float* W_kvd  = (const float*)d_in[4];
  const float* W_kvu  = (const float*)d_in[5];
  const float* W_out  = (const float*)d_in[6];
  float* out = (float*)d_out;

  // byte-offset workspace carve; top = 42 MB (proven footprint). q_bf dead.
  char* wsb = (char*)d_ws;
  u16* xq_bf   = (u16*)(wsb + 0);                            // 4 MB
  u16* wq_bf   = (u16*)(wsb + (4u << 20));                   // 2 MB
  u16* xkv_bf  = (u16*)(wsb + (6u << 20));                   // 8 MB
  u16* wkvd_bf = (u16*)(wsb + (14u << 20));                  // 256 KB
  u16* wkt     = (u16*)(wsb + (14u << 20) + (256u << 10));   // 256 KB
  u16* wv_bf   = (u16*)(wsb + (14u << 20) + (512u << 10));   // 256 KB
  u16* wout_bf = (u16*)(wsb + (14u << 20) + (768u << 10));   // 2 MB
  u16* c_kvb   = (u16*)(wsb + (21u << 20));                  // 1 MB
  u16* qlat_bf = (u16*)(wsb + (22u << 20));                  // 8 MB
  u16* cw_bf   = (u16*)(wsb + (30u << 20));                  // 8 MB
  u16* o_bf    = (u16*)(wsb + (38u << 20));                  // 4 MB

  // C0: all conversions in one dispatch
  megaconv<<<dim3(4288), 256, 0, stream>>>(x_q, W_q, x_kv, W_kvd, W_kvu, W_out,
                                           xq_bf, wq_bf, xkv_bf, wkvd_bf,
                                           wv_bf, wout_bf, wkt);

  // D1: K1+K3 fused (512 blocks) || K2 (128 blocks)
  d1_fused<<<dim3(640), 256, 0, stream>>>(xq_bf, wq_bf, xkv_bf, wkvd_bf,
                                          wkt, qlat_bf, c_kvb);

  // K4: fused gather + latent scores + softmax + latent PV (bf16 MFMA)
  attn_mfma<<<dim3(2048), 256, 0, stream>>>(c_kvb, qlat_bf, idx, cw_bf);

  // K5: o_bf[bq,h*64+n] = bf16(cw[bq,h,:] @ W_v[h]^T)  (BK=128, nk=1)
  gemm_nt_g4<<<dim3(1, 32, 16), 256, 0, stream>>>(
      cw_bf, 2048, 128, wv_bf, 128, 8192, nullptr, o_bf, 1024, 64, 128, 1);

  // K6: out = o @ W_out^T  (fp32 out, BK=128, nk=8)
  gemm_nt_g4<<<dim3(16, 32, 1), 256, 0, stream>>>(
      o_bf, 1024, 0, wout_bf, 1024, 0, out, nullptr, 1024, 0, 1024, 0);
}